// Round 2
// baseline (844.411 us; speedup 1.0000x reference)
//
#include <hip/hip_runtime.h>
#include <hip/hip_bf16.h>
#include <cstddef>

#define NN    50000
#define NE    800000
#define FIN   256
#define HID   64
#define NH    8
#define F1    512      // NH*HID
#define EMB   128
#define ALPHA 0.2f
#define EPSF  1e-16f

typedef __hip_bfloat16 bf16;

__device__ __forceinline__ float eluf(float x){ return x > 0.f ? x : expm1f(x); }
__device__ __forceinline__ float lrelu_neg_exp(float s){
    float lr = s > 0.f ? s : ALPHA * s;
    return __expf(-lr);
}

// ---------------- CSR build ----------------
__global__ void k_zero(int* p, int n){
    int i = blockIdx.x * 256 + threadIdx.x;
    if (i < n) p[i] = 0;
}

__global__ void k_count(const int* __restrict__ src, int* __restrict__ cnt){
    int e = blockIdx.x * 256 + threadIdx.x;
    if (e < NE) atomicAdd(&cnt[src[e]], 1);
}

// single-block exclusive scan of cnt[NN] -> row_ptr[NN+1]
__global__ __launch_bounds__(256) void k_scan(const int* __restrict__ cnt, int* __restrict__ rp){
    __shared__ int part[256];
    const int CH = (NN + 255) / 256;   // 196
    int t = threadIdx.x;
    int s = 0;
    for (int i = 0; i < CH; i++){
        int idx = t * CH + i;
        if (idx < NN) s += cnt[idx];
    }
    part[t] = s;
    __syncthreads();
    for (int o = 1; o < 256; o <<= 1){
        int v = (t >= o) ? part[t - o] : 0;
        __syncthreads();
        part[t] += v;
        __syncthreads();
    }
    int base = (t == 0) ? 0 : part[t - 1];
    for (int i = 0; i < CH; i++){
        int idx = t * CH + i;
        if (idx < NN){ rp[idx] = base; base += cnt[idx]; }
    }
    if (t == 255) rp[NN] = part[255];
}

__global__ void k_scatter(const int* __restrict__ src, const int* __restrict__ dst,
                          const int* __restrict__ rp, int* __restrict__ cur,
                          int* __restrict__ sdst){
    int e = blockIdx.x * 256 + threadIdx.x;
    if (e < NE){
        int s = src[e];
        int p = atomicAdd(&cur[s], 1);
        sdst[rp[s] + p] = dst[e];
    }
}

// ---------------- GEMM1: h1[n][f] = sum_k x[n][k] * W1[f/64][k][f%64] ----------------
#define G1_NPB 16
__global__ __launch_bounds__(256) void k_gemm1(const float* __restrict__ x,
                                               const float* __restrict__ W1,
                                               bf16* __restrict__ h1){
    __shared__ float xs[G1_NPB][FIN];          // 16 KiB
    const int t  = threadIdx.x;
    const int n0 = blockIdx.x * G1_NPB;
    const int f  = blockIdx.y * 256 + t;
    for (int i = 0; i < G1_NPB; i++)
        xs[i][t] = x[(size_t)(n0 + i) * FIN + t];
    __syncthreads();
    const int h = f >> 6, fl = f & 63;
    const float* Wp = W1 + (size_t)h * FIN * HID + fl;   // stride HID per k
    float acc[G1_NPB];
#pragma unroll
    for (int i = 0; i < G1_NPB; i++) acc[i] = 0.f;
#pragma unroll 4
    for (int k = 0; k < FIN; k++){
        float w = Wp[(size_t)k * HID];
#pragma unroll
        for (int i = 0; i < G1_NPB; i++) acc[i] += xs[i][k] * w;
    }
    for (int i = 0; i < G1_NPB; i++)
        h1[(size_t)(n0 + i) * F1 + f] = __float2bfloat16(acc[i]);
}

// ---------------- per-node attention scalars, layer 1 ----------------
__global__ void k_s1(const bf16* __restrict__ h1, const float* __restrict__ a1,
                     float* __restrict__ s11, float* __restrict__ s12){
    int idx = blockIdx.x * 256 + threadIdx.x;
    if (idx >= NN * NH) return;
    int n = idx >> 3, h = idx & 7;
    const bf16*  hp = h1 + (size_t)n * F1 + h * HID;
    const float* a  = a1 + (size_t)h * 2 * HID;
    float d1 = 0.f, d2 = 0.f;
    for (int j = 0; j < HID; j++){
        float v = __bfloat162float(hp[j]);
        d1 += v * a[j];
        d2 += v * a[HID + j];
    }
    s11[idx] = d1;   // layout [n][h]
    s12[idx] = d2;
}

// ---------------- layer-1 aggregation: x1 = elu(num/denom) ----------------
#define CHK 32
__global__ __launch_bounds__(256) void k_agg1(const bf16* __restrict__ h1,
                                              const float* __restrict__ s11,
                                              const float* __restrict__ s12,
                                              const int* __restrict__ rp,
                                              const int* __restrict__ sdst,
                                              bf16* __restrict__ x1){
    const int n = blockIdx.x, t = threadIdx.x;
    __shared__ float ee[CHK][NH];
    __shared__ int   db[CHK];
    __shared__ float dh[NH];
    __shared__ float s1l[NH];
    if (t < NH){ dh[t] = 0.f; s1l[t] = s11[n * NH + t]; }
    __syncthreads();
    const int start = rp[n], end = rp[n + 1];
    float acc0 = 0.f, acc1 = 0.f;
    const int f0 = t, f1 = t + 256;
    const int ha = f0 >> 6, hb = f1 >> 6;
    for (int e0 = start; e0 < end; e0 += CHK){
        const int m = min(CHK, end - e0);
        if (t < m) db[t] = sdst[e0 + t];
        __syncthreads();
        if (t < m * NH){
            int j = t >> 3, hh = t & 7;
            float sc = s1l[hh] + s12[db[j] * NH + hh];
            ee[j][hh] = lrelu_neg_exp(sc);
        }
        __syncthreads();
        if (t < NH){
            float s = 0.f;
            for (int j = 0; j < m; j++) s += ee[j][t];
            dh[t] += s;
        }
        for (int j = 0; j < m; j++){
            const bf16* hp = h1 + (size_t)db[j] * F1;
            acc0 += ee[j][ha] * __bfloat162float(hp[f0]);
            acc1 += ee[j][hb] * __bfloat162float(hp[f1]);
        }
        __syncthreads();
    }
    const float v0 = acc0 / (dh[ha] + EPSF);
    const float v1 = acc1 / (dh[hb] + EPSF);
    x1[(size_t)n * F1 + f0] = __float2bfloat16(eluf(v0));
    x1[(size_t)n * F1 + f1] = __float2bfloat16(eluf(v1));
}

// ---------------- GEMM2: h2 = x1 @ Wo ----------------
#define G2_NPB 16
__global__ __launch_bounds__(128) void k_gemm2(const bf16* __restrict__ x1,
                                               const float* __restrict__ Wo,
                                               float* __restrict__ h2){
    __shared__ float xs[G2_NPB][F1];           // 32 KiB
    const int t  = threadIdx.x;                // 128 threads
    const int n0 = blockIdx.x * G2_NPB;
    float* xsf = &xs[0][0];
    for (int i = t; i < G2_NPB * F1; i += 128)
        xsf[i] = __bfloat162float(x1[(size_t)n0 * F1 + i]);
    __syncthreads();
    float acc[G2_NPB];
#pragma unroll
    for (int i = 0; i < G2_NPB; i++) acc[i] = 0.f;
#pragma unroll 4
    for (int k = 0; k < F1; k++){
        float w = Wo[(size_t)k * EMB + t];
#pragma unroll
        for (int i = 0; i < G2_NPB; i++) acc[i] += xs[i][k] * w;
    }
    for (int i = 0; i < G2_NPB; i++)
        h2[(size_t)(n0 + i) * EMB + t] = acc[i];
}

// ---------------- per-node attention scalars, layer 2 ----------------
__global__ void k_s2(const float* __restrict__ h2, const float* __restrict__ ao,
                     float* __restrict__ s21, float* __restrict__ s22){
    int n = blockIdx.x * 256 + threadIdx.x;
    if (n >= NN) return;
    const float* hp = h2 + (size_t)n * EMB;
    float d1 = 0.f, d2 = 0.f;
    for (int j = 0; j < EMB; j++){
        float v = hp[j];
        d1 += v * ao[j];
        d2 += v * ao[EMB + j];
    }
    s21[n] = d1;
    s22[n] = d2;
}

// ---------------- layer-2 aggregation: out0 = elu(num/denom), save denom ----------------
__global__ __launch_bounds__(128) void k_agg2(const float* __restrict__ h2,
                                              const float* __restrict__ s21,
                                              const float* __restrict__ s22,
                                              const int* __restrict__ rp,
                                              const int* __restrict__ sdst,
                                              float* __restrict__ den2,
                                              float* __restrict__ out0){
    const int n = blockIdx.x, t = threadIdx.x;   // 128 threads
    __shared__ float ee[CHK];
    __shared__ int   db[CHK];
    __shared__ float dhs;
    if (t == 0) dhs = 0.f;
    __syncthreads();
    const float s1v = s21[n];
    const int start = rp[n], end = rp[n + 1];
    float acc = 0.f;
    for (int e0 = start; e0 < end; e0 += CHK){
        const int m = min(CHK, end - e0);
        if (t < m){
            int d = sdst[e0 + t];
            db[t] = d;
            ee[t] = lrelu_neg_exp(s1v + s22[d]);
        }
        __syncthreads();
        if (t == 0){
            float s = 0.f;
            for (int j = 0; j < m; j++) s += ee[j];
            dhs += s;
        }
        for (int j = 0; j < m; j++)
            acc += ee[j] * h2[(size_t)db[j] * EMB + t];
        __syncthreads();
    }
    const float den = dhs + EPSF;
    out0[(size_t)n * EMB + t] = eluf(acc / den);
    if (t == 0) den2[n] = den;
}

// ---------------- att_out in original edge order ----------------
__global__ void k_att(const int* __restrict__ src, const int* __restrict__ dst,
                      const float* __restrict__ s21, const float* __restrict__ s22,
                      const float* __restrict__ den2, float* __restrict__ outA){
    int e = blockIdx.x * 256 + threadIdx.x;
    if (e >= NE) return;
    int s = src[e], d = dst[e];
    float ee = lrelu_neg_exp(s21[s] + s22[d]);
    outA[e] = ee / den2[s];
}

__global__ void k_edgecopy(const int* __restrict__ ei, float* __restrict__ outE){
    int i = blockIdx.x * 256 + threadIdx.x;
    if (i < 2 * NE) outE[i] = (float)ei[i];
}

// ---------------- launch ----------------
extern "C" void kernel_launch(void* const* d_in, const int* in_sizes, int n_in,
                              void* d_out, int out_size, void* d_ws, size_t ws_size,
                              hipStream_t stream){
    const float* x  = (const float*)d_in[0];
    const int*   ei = (const int*)d_in[1];
    const float* W1 = (const float*)d_in[2];
    const float* a1 = (const float*)d_in[3];
    const float* Wo = (const float*)d_in[4];
    const float* ao = (const float*)d_in[5];
    float* out = (float*)d_out;                 // fp32 output buffer
    const int* src = ei;
    const int* dst = ei + NE;

    char* w = (char*)d_ws;
    auto alloc = [&](size_t bytes) -> char* {
        char* p = w;
        w += (bytes + 255) & ~(size_t)255;
        return p;
    };
    bf16*  h1    = (bf16*) alloc((size_t)NN * F1 * 2);   // 51.2 MB
    bf16*  x1    = (bf16*) alloc((size_t)NN * F1 * 2);   // 51.2 MB
    float* s11   = (float*)alloc((size_t)NN * NH * 4);
    float* s12   = (float*)alloc((size_t)NN * NH * 4);
    float* s21   = (float*)alloc((size_t)NN * 4);
    float* s22   = (float*)alloc((size_t)NN * 4);
    float* den2  = (float*)alloc((size_t)NN * 4);
    int*   cnt2  = (int*)  alloc((size_t)2 * NN * 4);    // cnt | cur contiguous
    int*   rp    = (int*)  alloc((size_t)(NN + 1) * 4);
    int*   sdst  = (int*)  alloc((size_t)NE * 4);
    int*   cnt = cnt2;
    int*   cur = cnt2 + NN;
    // h2 reuses h1's region (h1 dead after k_agg1): 25.6 MB fp32 fits in 51.2 MB
    float* h2 = (float*)h1;
    // total ~110 MB of d_ws

    // CSR build
    k_zero   <<<(2 * NN + 255) / 256, 256, 0, stream>>>(cnt2, 2 * NN);
    k_count  <<<(NE + 255) / 256,     256, 0, stream>>>(src, cnt);
    k_scan   <<<1,                    256, 0, stream>>>(cnt, rp);
    k_scatter<<<(NE + 255) / 256,     256, 0, stream>>>(src, dst, rp, cur, sdst);

    // layer 1
    dim3 g1(NN / G1_NPB, 2);
    k_gemm1<<<g1, 256, 0, stream>>>(x, W1, h1);
    k_s1   <<<(NN * NH + 255) / 256, 256, 0, stream>>>(h1, a1, s11, s12);
    k_agg1 <<<NN, 256, 0, stream>>>(h1, s11, s12, rp, sdst, x1);

    // layer 2
    k_gemm2<<<NN / G2_NPB, 128, 0, stream>>>(x1, Wo, h2);
    k_s2   <<<(NN + 255) / 256, 256, 0, stream>>>(h2, ao, s21, s22);
    k_agg2 <<<NN, 128, 0, stream>>>(h2, s21, s22, rp, sdst, den2, out);

    // outputs 1 & 2 (float element offsets)
    k_att     <<<(NE + 255) / 256,     256, 0, stream>>>(src, dst, s21, s22, den2,
                                                         out + (size_t)NN * EMB + 2 * NE);
    k_edgecopy<<<(2 * NE + 255) / 256, 256, 0, stream>>>(ei, out + (size_t)NN * EMB);
}

// Round 3
// 492.731 us; speedup vs baseline: 1.7137x; 1.7137x over previous
//
#include <hip/hip_runtime.h>
#include <hip/hip_bf16.h>
#include <cstddef>

#define NN    50000
#define NE    800000
#define FIN   256
#define HID   64
#define NH    8
#define F1    512      // NH*HID
#define EMB   128
#define ALPHA 0.2f
#define EPSF  1e-16f

typedef __hip_bfloat16 bf16;
typedef __attribute__((ext_vector_type(8))) short short8;
typedef __attribute__((ext_vector_type(4))) float f32x4;

__device__ __forceinline__ float eluf(float x){ return x > 0.f ? x : expm1f(x); }
__device__ __forceinline__ float lrelu_neg_exp(float s){
    float lr = s > 0.f ? s : ALPHA * s;
    return __expf(-lr);
}
__device__ __forceinline__ float b2f(unsigned u){ return __uint_as_float(u << 16); }

// ---------------- input conversions ----------------
__global__ void k_cvt_x(const float* __restrict__ x, bf16* __restrict__ xb){
    int i = blockIdx.x * 256 + threadIdx.x;          // one thread = 8 elems
    if (i >= NN * FIN / 8) return;
    const float4* xp = (const float4*)(x + (size_t)i * 8);
    float4 v0 = xp[0], v1 = xp[1];
    bf16 o[8];
    o[0] = __float2bfloat16(v0.x); o[1] = __float2bfloat16(v0.y);
    o[2] = __float2bfloat16(v0.z); o[3] = __float2bfloat16(v0.w);
    o[4] = __float2bfloat16(v1.x); o[5] = __float2bfloat16(v1.y);
    o[6] = __float2bfloat16(v1.z); o[7] = __float2bfloat16(v1.w);
    *(uint4*)(xb + (size_t)i * 8) = *(uint4*)o;
}

// Bt1[n][k] = W1[n>>6][k][n&63]   (512 x 256, bf16)
__global__ void k_tw1(const float* __restrict__ W1, bf16* __restrict__ Bt1){
    int i = blockIdx.x * 256 + threadIdx.x;
    if (i >= F1 * FIN) return;
    int n = i >> 8, k = i & 255;
    Bt1[i] = __float2bfloat16(W1[(size_t)(n >> 6) * FIN * HID + (size_t)k * HID + (n & 63)]);
}

// WoT[n][k] = Wo[k][n]   (128 x 512, bf16)
__global__ void k_tw2(const float* __restrict__ Wo, bf16* __restrict__ WoT){
    int i = blockIdx.x * 256 + threadIdx.x;
    if (i >= EMB * F1) return;
    int n = i >> 9, k = i & 511;
    WoT[i] = __float2bfloat16(Wo[(size_t)k * EMB + n]);
}

// ---------------- CSR build ----------------
__global__ void k_zero(int* p, int n){
    int i = blockIdx.x * 256 + threadIdx.x;
    if (i < n) p[i] = 0;
}

__global__ void k_count(const int* __restrict__ src, int* __restrict__ cnt){
    int e = blockIdx.x * 256 + threadIdx.x;
    if (e < NE) atomicAdd(&cnt[src[e]], 1);
}

__global__ __launch_bounds__(256) void k_scan(const int* __restrict__ cnt, int* __restrict__ rp){
    __shared__ int part[256];
    const int CH = (NN + 255) / 256;   // 196
    int t = threadIdx.x;
    int s = 0;
    for (int i = 0; i < CH; i++){
        int idx = t * CH + i;
        if (idx < NN) s += cnt[idx];
    }
    part[t] = s;
    __syncthreads();
    for (int o = 1; o < 256; o <<= 1){
        int v = (t >= o) ? part[t - o] : 0;
        __syncthreads();
        part[t] += v;
        __syncthreads();
    }
    int base = (t == 0) ? 0 : part[t - 1];
    for (int i = 0; i < CH; i++){
        int idx = t * CH + i;
        if (idx < NN){ rp[idx] = base; base += cnt[idx]; }
    }
    if (t == 255) rp[NN] = part[255];
}

__global__ void k_scatter(const int* __restrict__ src, const int* __restrict__ dst,
                          const int* __restrict__ rp, int* __restrict__ cur,
                          int* __restrict__ sdst){
    int e = blockIdx.x * 256 + threadIdx.x;
    if (e < NE){
        int s = src[e];
        int p = atomicAdd(&cur[s], 1);
        sdst[rp[s] + p] = dst[e];
    }
}

// ---------------- MFMA GEMM: C[M][N] = A[M][K] @ B^T[N][K], bf16 in/out ----------------
// 128x128 block tile, 4 waves each 64x64 (4x4 frags of 16x16x32).
template<int K>
__global__ __launch_bounds__(256) void k_mgemm(const bf16* __restrict__ A,
                                               const bf16* __restrict__ B,
                                               bf16* __restrict__ C,
                                               int N){
    constexpr int LDT = 40;                     // bf16 elems per LDS row (80B, conflict-free)
    __shared__ __align__(16) bf16 As[128 * LDT];
    __shared__ __align__(16) bf16 Bs[128 * LDT];
    const int t = threadIdx.x;
    const int lane = t & 63, wid = t >> 6;
    const int m0 = blockIdx.x * 128, n0 = blockIdx.y * 128;
    // staging: thread covers units t and t+256 (unit = 16B of a 64B row-slice)
    const int r0 = t >> 2, u0 = t & 3;          // rows 0..63
    const int r1 = r0 + 64;                     // rows 64..127
    // fragment indices
    const int rb = (wid & 1) * 64, cb = (wid >> 1) * 64;
    const int fr = lane & 15, fk = (lane >> 4) * 8;

    f32x4 acc[4][4];
#pragma unroll
    for (int i = 0; i < 4; i++)
#pragma unroll
        for (int j = 0; j < 4; j++) acc[i][j] = (f32x4)(0.f);

    for (int k0 = 0; k0 < K; k0 += 32){
        const int ga0 = m0 + r0, ga1 = m0 + r1;
        uint4 av0 = (ga0 < NN) ? *(const uint4*)(A + (size_t)ga0 * K + k0 + u0 * 8)
                               : make_uint4(0, 0, 0, 0);
        uint4 av1 = (ga1 < NN) ? *(const uint4*)(A + (size_t)ga1 * K + k0 + u0 * 8)
                               : make_uint4(0, 0, 0, 0);
        uint4 bv0 = *(const uint4*)(B + (size_t)(n0 + r0) * K + k0 + u0 * 8);
        uint4 bv1 = *(const uint4*)(B + (size_t)(n0 + r1) * K + k0 + u0 * 8);
        __syncthreads();
        *(uint4*)(As + r0 * LDT + u0 * 8) = av0;
        *(uint4*)(As + r1 * LDT + u0 * 8) = av1;
        *(uint4*)(Bs + r0 * LDT + u0 * 8) = bv0;
        *(uint4*)(Bs + r1 * LDT + u0 * 8) = bv1;
        __syncthreads();
        short8 af[4], bf_[4];
#pragma unroll
        for (int i = 0; i < 4; i++){
            af[i]  = *(const short8*)(As + (rb + i * 16 + fr) * LDT + fk);
            bf_[i] = *(const short8*)(Bs + (cb + i * 16 + fr) * LDT + fk);
        }
#pragma unroll
        for (int i = 0; i < 4; i++)
#pragma unroll
            for (int j = 0; j < 4; j++)
                acc[i][j] = __builtin_amdgcn_mfma_f32_16x16x32_bf16(af[i], bf_[j], acc[i][j], 0, 0, 0);
    }
    // epilogue: C[row][col], row=(lane>>4)*4+v, col=lane&15 within each 16x16 frag
    const int crow = m0 + rb + (lane >> 4) * 4;
    const int ccol = n0 + cb + (lane & 15);
#pragma unroll
    for (int i = 0; i < 4; i++)
#pragma unroll
        for (int j = 0; j < 4; j++)
#pragma unroll
            for (int v = 0; v < 4; v++){
                int row = crow + i * 16 + v;
                if (row < NN)
                    C[(size_t)row * N + ccol + j * 16] = __float2bfloat16(acc[i][j][v]);
            }
}

// ---------------- per-node attention scalars, layer 1 ----------------
__global__ void k_s1(const bf16* __restrict__ h1, const float* __restrict__ a1,
                     float* __restrict__ s11, float* __restrict__ s12){
    int idx = blockIdx.x * 256 + threadIdx.x;
    if (idx >= NN * NH) return;
    int n = idx >> 3, h = idx & 7;
    const uint4* hp = (const uint4*)(h1 + (size_t)n * F1 + h * HID);
    const float* a  = a1 + (size_t)h * 2 * HID;
    float d1 = 0.f, d2 = 0.f;
#pragma unroll
    for (int u = 0; u < 8; u++){
        uint4 v = hp[u];
        int j = u * 8;
        float f0 = b2f(v.x & 0xffffu), f1 = b2f(v.x >> 16);
        float f2 = b2f(v.y & 0xffffu), f3 = b2f(v.y >> 16);
        float f4 = b2f(v.z & 0xffffu), f5 = b2f(v.z >> 16);
        float f6 = b2f(v.w & 0xffffu), f7 = b2f(v.w >> 16);
        d1 += f0 * a[j]     + f1 * a[j + 1] + f2 * a[j + 2] + f3 * a[j + 3]
            + f4 * a[j + 4] + f5 * a[j + 5] + f6 * a[j + 6] + f7 * a[j + 7];
        d2 += f0 * a[HID + j]     + f1 * a[HID + j + 1] + f2 * a[HID + j + 2] + f3 * a[HID + j + 3]
            + f4 * a[HID + j + 4] + f5 * a[HID + j + 5] + f6 * a[HID + j + 6] + f7 * a[HID + j + 7];
    }
    s11[idx] = d1;   // layout [n][h]
    s12[idx] = d2;
}

// ---------------- layer-1 aggregation: x1 = elu(num/denom) ----------------
#define CHK 32
__global__ __launch_bounds__(256) void k_agg1(const bf16* __restrict__ h1,
                                              const float* __restrict__ s11,
                                              const float* __restrict__ s12,
                                              const int* __restrict__ rp,
                                              const int* __restrict__ sdst,
                                              bf16* __restrict__ x1){
    const int n = blockIdx.x, t = threadIdx.x;
    __shared__ float ee[CHK][NH];
    __shared__ int   db[CHK];
    __shared__ float dh[NH];
    __shared__ float s1l[NH];
    if (t < NH){ dh[t] = 0.f; s1l[t] = s11[n * NH + t]; }
    __syncthreads();
    const int start = rp[n], end = rp[n + 1];
    float acc0 = 0.f, acc1 = 0.f;
    const int f0 = t, f1 = t + 256;
    const int ha = f0 >> 6, hb = f1 >> 6;
    for (int e0 = start; e0 < end; e0 += CHK){
        const int m = min(CHK, end - e0);
        if (t < m) db[t] = sdst[e0 + t];
        __syncthreads();
        if (t < m * NH){
            int j = t >> 3, hh = t & 7;
            float sc = s1l[hh] + s12[db[j] * NH + hh];
            ee[j][hh] = lrelu_neg_exp(sc);
        }
        __syncthreads();
        if (t < NH){
            float s = 0.f;
            for (int j = 0; j < m; j++) s += ee[j][t];
            dh[t] += s;
        }
        for (int j = 0; j < m; j++){
            const bf16* hp = h1 + (size_t)db[j] * F1;
            acc0 += ee[j][ha] * __bfloat162float(hp[f0]);
            acc1 += ee[j][hb] * __bfloat162float(hp[f1]);
        }
        __syncthreads();
    }
    const float v0 = acc0 / (dh[ha] + EPSF);
    const float v1 = acc1 / (dh[hb] + EPSF);
    x1[(size_t)n * F1 + f0] = __float2bfloat16(eluf(v0));
    x1[(size_t)n * F1 + f1] = __float2bfloat16(eluf(v1));
}

// ---------------- per-node attention scalars, layer 2 (bf16 h2) ----------------
__global__ void k_s2(const bf16* __restrict__ h2, const float* __restrict__ ao,
                     float* __restrict__ s21, float* __restrict__ s22){
    int n = blockIdx.x * 256 + threadIdx.x;
    if (n >= NN) return;
    const uint4* hp = (const uint4*)(h2 + (size_t)n * EMB);
    float d1 = 0.f, d2 = 0.f;
#pragma unroll
    for (int u = 0; u < 16; u++){
        uint4 v = hp[u];
        int j = u * 8;
        float f0 = b2f(v.x & 0xffffu), f1 = b2f(v.x >> 16);
        float f2 = b2f(v.y & 0xffffu), f3 = b2f(v.y >> 16);
        float f4 = b2f(v.z & 0xffffu), f5 = b2f(v.z >> 16);
        float f6 = b2f(v.w & 0xffffu), f7 = b2f(v.w >> 16);
        d1 += f0 * ao[j]     + f1 * ao[j + 1] + f2 * ao[j + 2] + f3 * ao[j + 3]
            + f4 * ao[j + 4] + f5 * ao[j + 5] + f6 * ao[j + 6] + f7 * ao[j + 7];
        d2 += f0 * ao[EMB + j]     + f1 * ao[EMB + j + 1] + f2 * ao[EMB + j + 2] + f3 * ao[EMB + j + 3]
            + f4 * ao[EMB + j + 4] + f5 * ao[EMB + j + 5] + f6 * ao[EMB + j + 6] + f7 * ao[EMB + j + 7];
    }
    s21[n] = d1;
    s22[n] = d2;
}

// ---------------- layer-2 aggregation ----------------
__global__ __launch_bounds__(128) void k_agg2(const bf16* __restrict__ h2,
                                              const float* __restrict__ s21,
                                              const float* __restrict__ s22,
                                              const int* __restrict__ rp,
                                              const int* __restrict__ sdst,
                                              float* __restrict__ den2,
                                              float* __restrict__ out0){
    const int n = blockIdx.x, t = threadIdx.x;   // 128 threads
    __shared__ float ee[CHK];
    __shared__ int   db[CHK];
    __shared__ float dhs;
    if (t == 0) dhs = 0.f;
    __syncthreads();
    const float s1v = s21[n];
    const int start = rp[n], end = rp[n + 1];
    float acc = 0.f;
    for (int e0 = start; e0 < end; e0 += CHK){
        const int m = min(CHK, end - e0);
        if (t < m){
            int d = sdst[e0 + t];
            db[t] = d;
            ee[t] = lrelu_neg_exp(s1v + s22[d]);
        }
        __syncthreads();
        if (t == 0){
            float s = 0.f;
            for (int j = 0; j < m; j++) s += ee[j];
            dhs += s;
        }
        for (int j = 0; j < m; j++)
            acc += ee[j] * __bfloat162float(h2[(size_t)db[j] * EMB + t]);
        __syncthreads();
    }
    const float den = dhs + EPSF;
    out0[(size_t)n * EMB + t] = eluf(acc / den);
    if (t == 0) den2[n] = den;
}

// ---------------- att_out in original edge order ----------------
__global__ void k_att(const int* __restrict__ src, const int* __restrict__ dst,
                      const float* __restrict__ s21, const float* __restrict__ s22,
                      const float* __restrict__ den2, float* __restrict__ outA){
    int e = blockIdx.x * 256 + threadIdx.x;
    if (e >= NE) return;
    int s = src[e], d = dst[e];
    float ee = lrelu_neg_exp(s21[s] + s22[d]);
    outA[e] = ee / den2[s];
}

__global__ void k_edgecopy(const int* __restrict__ ei, float* __restrict__ outE){
    int i = blockIdx.x * 256 + threadIdx.x;
    if (i < 2 * NE) outE[i] = (float)ei[i];
}

// ---------------- launch ----------------
extern "C" void kernel_launch(void* const* d_in, const int* in_sizes, int n_in,
                              void* d_out, int out_size, void* d_ws, size_t ws_size,
                              hipStream_t stream){
    const float* x  = (const float*)d_in[0];
    const int*   ei = (const int*)d_in[1];
    const float* W1 = (const float*)d_in[2];
    const float* a1 = (const float*)d_in[3];
    const float* Wo = (const float*)d_in[4];
    const float* ao = (const float*)d_in[5];
    float* out = (float*)d_out;
    const int* src = ei;
    const int* dst = ei + NE;

    char* w = (char*)d_ws;
    auto alloc = [&](size_t bytes) -> char* {
        char* p = w;
        w += (bytes + 255) & ~(size_t)255;
        return p;
    };
    bf16*  xb   = (bf16*) alloc((size_t)NN * FIN * 2);  // 25.6 MB
    bf16*  h1   = (bf16*) alloc((size_t)NN * F1 * 2);   // 51.2 MB
    bf16*  x1   = (bf16*) alloc((size_t)NN * F1 * 2);   // 51.2 MB
    float* s11  = (float*)alloc((size_t)NN * NH * 4);
    float* s12  = (float*)alloc((size_t)NN * NH * 4);
    float* s21  = (float*)alloc((size_t)NN * 4);
    float* s22  = (float*)alloc((size_t)NN * 4);
    float* den2 = (float*)alloc((size_t)NN * 4);
    int*   cnt2 = (int*)  alloc((size_t)2 * NN * 4);
    int*   rp   = (int*)  alloc((size_t)(NN + 1) * 4);
    int*   sdst = (int*)  alloc((size_t)NE * 4);
    int*   cnt = cnt2;
    int*   cur = cnt2 + NN;
    // lifetime-disjoint aliases (keeps total at ~135.6 MB):
    bf16* Bt1 = x1;                 // dead before k_agg1 writes x1
    bf16* WoT = (bf16*)s21;         // dead before k_s2 writes s21
    bf16* h2  = h1;                 // h1 dead after k_agg1

    // input conversion / weight transposes
    k_cvt_x<<<(NN * FIN / 8 + 255) / 256, 256, 0, stream>>>(x, xb);
    k_tw1  <<<(F1 * FIN + 255) / 256,     256, 0, stream>>>(W1, Bt1);
    k_tw2  <<<(EMB * F1 + 255) / 256,     256, 0, stream>>>(Wo, WoT);

    // CSR build
    k_zero   <<<(2 * NN + 255) / 256, 256, 0, stream>>>(cnt2, 2 * NN);
    k_count  <<<(NE + 255) / 256,     256, 0, stream>>>(src, cnt);
    k_scan   <<<1,                    256, 0, stream>>>(cnt, rp);
    k_scatter<<<(NE + 255) / 256,     256, 0, stream>>>(src, dst, rp, cur, sdst);

    // layer 1
    k_mgemm<FIN><<<dim3((NN + 127) / 128, F1 / 128), 256, 0, stream>>>(xb, Bt1, h1, F1);
    k_s1  <<<(NN * NH + 255) / 256, 256, 0, stream>>>(h1, a1, s11, s12);
    k_agg1<<<NN, 256, 0, stream>>>(h1, s11, s12, rp, sdst, x1);

    // layer 2
    k_mgemm<F1><<<dim3((NN + 127) / 128, EMB / 128), 256, 0, stream>>>(x1, WoT, h2, EMB);
    k_s2  <<<(NN + 255) / 256, 256, 0, stream>>>(h2, ao, s21, s22);
    k_agg2<<<NN, 128, 0, stream>>>(h2, s21, s22, rp, sdst, den2, out);

    // outputs 1 & 2
    k_att     <<<(NE + 255) / 256,     256, 0, stream>>>(src, dst, s21, s22, den2,
                                                         out + (size_t)NN * EMB + 2 * NE);
    k_edgecopy<<<(2 * NE + 255) / 256, 256, 0, stream>>>(ei, out + (size_t)NN * EMB);
}

// Round 4
// 470.350 us; speedup vs baseline: 1.7953x; 1.0476x over previous
//
#include <hip/hip_runtime.h>
#include <hip/hip_bf16.h>
#include <cstddef>

#define NN    50000
#define NE    800000
#define FIN   256
#define HID   64
#define NH    8
#define F1    512      // NH*HID
#define EMB   128
#define ALPHA 0.2f
#define EPSF  1e-16f

typedef __hip_bfloat16 bf16;
typedef __attribute__((ext_vector_type(8))) short short8;
typedef __attribute__((ext_vector_type(4))) float f32x4;

__device__ __forceinline__ float eluf(float x){ return x > 0.f ? x : expm1f(x); }
__device__ __forceinline__ float lrelu_neg_exp(float s){
    float lr = s > 0.f ? s : ALPHA * s;
    return __expf(-lr);
}
__device__ __forceinline__ float b2f(unsigned u){ return __uint_as_float(u << 16); }

// acc[0..7] += e * bf16x8(v)
__device__ __forceinline__ void fma8(float* acc, uint4 v, float e){
    acc[0] += e * __uint_as_float(v.x << 16);
    acc[1] += e * __uint_as_float(v.x & 0xffff0000u);
    acc[2] += e * __uint_as_float(v.y << 16);
    acc[3] += e * __uint_as_float(v.y & 0xffff0000u);
    acc[4] += e * __uint_as_float(v.z << 16);
    acc[5] += e * __uint_as_float(v.z & 0xffff0000u);
    acc[6] += e * __uint_as_float(v.w << 16);
    acc[7] += e * __uint_as_float(v.w & 0xffff0000u);
}
// pack two floats as bf16 pair (RNE)
__device__ __forceinline__ unsigned bpack(float a, float b){
    unsigned ua = __float_as_uint(a), ub = __float_as_uint(b);
    ua = (ua + 0x7fffu + ((ua >> 16) & 1)) >> 16;
    ub = (ub + 0x7fffu + ((ub >> 16) & 1)) >> 16;
    return (ua & 0xffffu) | (ub << 16);
}

// ---------------- input conversions ----------------
__global__ void k_cvt_x(const float* __restrict__ x, bf16* __restrict__ xb){
    int i = blockIdx.x * 256 + threadIdx.x;          // one thread = 8 elems
    if (i >= NN * FIN / 8) return;
    const float4* xp = (const float4*)(x + (size_t)i * 8);
    float4 v0 = xp[0], v1 = xp[1];
    uint4 o;
    o.x = bpack(v0.x, v0.y); o.y = bpack(v0.z, v0.w);
    o.z = bpack(v1.x, v1.y); o.w = bpack(v1.z, v1.w);
    *(uint4*)(xb + (size_t)i * 8) = o;
}

// Bt1[n][k] = W1[n>>6][k][n&63]   (512 x 256, bf16)
__global__ void k_tw1(const float* __restrict__ W1, bf16* __restrict__ Bt1){
    int i = blockIdx.x * 256 + threadIdx.x;
    if (i >= F1 * FIN) return;
    int n = i >> 8, k = i & 255;
    Bt1[i] = __float2bfloat16(W1[(size_t)(n >> 6) * FIN * HID + (size_t)k * HID + (n & 63)]);
}

// WoT[n][k] = Wo[k][n]   (128 x 512, bf16)
__global__ void k_tw2(const float* __restrict__ Wo, bf16* __restrict__ WoT){
    int i = blockIdx.x * 256 + threadIdx.x;
    if (i >= EMB * F1) return;
    int n = i >> 9, k = i & 511;
    WoT[i] = __float2bfloat16(Wo[(size_t)k * EMB + n]);
}

// ---------------- CSR build ----------------
__global__ void k_zero(int* p, int n){
    int i = blockIdx.x * 256 + threadIdx.x;
    if (i < n) p[i] = 0;
}

__global__ void k_count(const int* __restrict__ src, int* __restrict__ cnt){
    int e = blockIdx.x * 256 + threadIdx.x;
    if (e < NE) atomicAdd(&cnt[src[e]], 1);
}

__global__ __launch_bounds__(256) void k_scan(const int* __restrict__ cnt, int* __restrict__ rp){
    __shared__ int part[256];
    const int CH = (NN + 255) / 256;   // 196
    int t = threadIdx.x;
    int s = 0;
    for (int i = 0; i < CH; i++){
        int idx = t * CH + i;
        if (idx < NN) s += cnt[idx];
    }
    part[t] = s;
    __syncthreads();
    for (int o = 1; o < 256; o <<= 1){
        int v = (t >= o) ? part[t - o] : 0;
        __syncthreads();
        part[t] += v;
        __syncthreads();
    }
    int base = (t == 0) ? 0 : part[t - 1];
    for (int i = 0; i < CH; i++){
        int idx = t * CH + i;
        if (idx < NN){ rp[idx] = base; base += cnt[idx]; }
    }
    if (t == 255) rp[NN] = part[255];
}

__global__ void k_scatter(const int* __restrict__ src, const int* __restrict__ dst,
                          const int* __restrict__ rp, int* __restrict__ cur,
                          int* __restrict__ sdst){
    int e = blockIdx.x * 256 + threadIdx.x;
    if (e < NE){
        int s = src[e];
        int p = atomicAdd(&cur[s], 1);
        sdst[rp[s] + p] = dst[e];
    }
}

// ---------------- MFMA GEMM: C[M][N] = A[M][K] @ B^T[N][K], bf16 in/out ----------------
template<int K>
__global__ __launch_bounds__(256) void k_mgemm(const bf16* __restrict__ A,
                                               const bf16* __restrict__ B,
                                               bf16* __restrict__ C,
                                               int N){
    constexpr int LDT = 40;                     // bf16 elems per LDS row (80B, conflict-free)
    __shared__ __align__(16) bf16 As[128 * LDT];
    __shared__ __align__(16) bf16 Bs[128 * LDT];
    const int t = threadIdx.x;
    const int lane = t & 63, wid = t >> 6;
    const int m0 = blockIdx.x * 128, n0 = blockIdx.y * 128;
    const int r0 = t >> 2, u0 = t & 3;          // rows 0..63
    const int r1 = r0 + 64;                     // rows 64..127
    const int rb = (wid & 1) * 64, cb = (wid >> 1) * 64;
    const int fr = lane & 15, fk = (lane >> 4) * 8;

    f32x4 acc[4][4];
#pragma unroll
    for (int i = 0; i < 4; i++)
#pragma unroll
        for (int j = 0; j < 4; j++) acc[i][j] = (f32x4)(0.f);

    for (int k0 = 0; k0 < K; k0 += 32){
        const int ga0 = m0 + r0, ga1 = m0 + r1;
        uint4 av0 = (ga0 < NN) ? *(const uint4*)(A + (size_t)ga0 * K + k0 + u0 * 8)
                               : make_uint4(0, 0, 0, 0);
        uint4 av1 = (ga1 < NN) ? *(const uint4*)(A + (size_t)ga1 * K + k0 + u0 * 8)
                               : make_uint4(0, 0, 0, 0);
        uint4 bv0 = *(const uint4*)(B + (size_t)(n0 + r0) * K + k0 + u0 * 8);
        uint4 bv1 = *(const uint4*)(B + (size_t)(n0 + r1) * K + k0 + u0 * 8);
        __syncthreads();
        *(uint4*)(As + r0 * LDT + u0 * 8) = av0;
        *(uint4*)(As + r1 * LDT + u0 * 8) = av1;
        *(uint4*)(Bs + r0 * LDT + u0 * 8) = bv0;
        *(uint4*)(Bs + r1 * LDT + u0 * 8) = bv1;
        __syncthreads();
        short8 af[4], bf_[4];
#pragma unroll
        for (int i = 0; i < 4; i++){
            af[i]  = *(const short8*)(As + (rb + i * 16 + fr) * LDT + fk);
            bf_[i] = *(const short8*)(Bs + (cb + i * 16 + fr) * LDT + fk);
        }
#pragma unroll
        for (int i = 0; i < 4; i++)
#pragma unroll
            for (int j = 0; j < 4; j++)
                acc[i][j] = __builtin_amdgcn_mfma_f32_16x16x32_bf16(af[i], bf_[j], acc[i][j], 0, 0, 0);
    }
    const int crow = m0 + rb + (lane >> 4) * 4;
    const int ccol = n0 + cb + (lane & 15);
#pragma unroll
    for (int i = 0; i < 4; i++)
#pragma unroll
        for (int j = 0; j < 4; j++)
#pragma unroll
            for (int v = 0; v < 4; v++){
                int row = crow + i * 16 + v;
                if (row < NN)
                    C[(size_t)row * N + ccol + j * 16] = __float2bfloat16(acc[i][j][v]);
            }
}

// ---------------- per-node attention scalars, layer 1 ----------------
__global__ void k_s1(const bf16* __restrict__ h1, const float* __restrict__ a1,
                     float* __restrict__ s11, float* __restrict__ s12){
    int idx = blockIdx.x * 256 + threadIdx.x;
    if (idx >= NN * NH) return;
    int n = idx >> 3, h = idx & 7;
    const uint4* hp = (const uint4*)(h1 + (size_t)n * F1 + h * HID);
    const float* a  = a1 + (size_t)h * 2 * HID;
    float d1 = 0.f, d2 = 0.f;
#pragma unroll
    for (int u = 0; u < 8; u++){
        uint4 v = hp[u];
        int j = u * 8;
        float f0 = b2f(v.x & 0xffffu), f1 = b2f(v.x >> 16);
        float f2 = b2f(v.y & 0xffffu), f3 = b2f(v.y >> 16);
        float f4 = b2f(v.z & 0xffffu), f5 = b2f(v.z >> 16);
        float f6 = b2f(v.w & 0xffffu), f7 = b2f(v.w >> 16);
        d1 += f0 * a[j]     + f1 * a[j + 1] + f2 * a[j + 2] + f3 * a[j + 3]
            + f4 * a[j + 4] + f5 * a[j + 5] + f6 * a[j + 6] + f7 * a[j + 7];
        d2 += f0 * a[HID + j]     + f1 * a[HID + j + 1] + f2 * a[HID + j + 2] + f3 * a[HID + j + 3]
            + f4 * a[HID + j + 4] + f5 * a[HID + j + 5] + f6 * a[HID + j + 6] + f7 * a[HID + j + 7];
    }
    s11[idx] = d1;   // layout [n][h]
    s12[idx] = d2;
}

// ---------------- layer-1 aggregation: one WAVE per node ----------------
// lane owns features lane*8..lane*8+7 (all in head lane>>3); ee & denom are lane-local.
__global__ __launch_bounds__(256) void k_agg1(const bf16* __restrict__ h1,
                                              const float* __restrict__ s11,
                                              const float* __restrict__ s12,
                                              const int* __restrict__ rp,
                                              const int* __restrict__ sdst,
                                              bf16* __restrict__ x1){
    const int t = threadIdx.x, lane = t & 63, w = t >> 6;
    const int n = blockIdx.x * 4 + w;
    const int h = lane >> 3;
    const float s1l = s11[n * NH + h];
    float acc[8] = {0.f,0.f,0.f,0.f,0.f,0.f,0.f,0.f};
    float ded = 0.f;
    const int start = rp[n], end = rp[n + 1];
    for (int c0 = start; c0 < end; c0 += 64){
        const int m = min(64, end - c0);
        int dreg = (lane < m) ? sdst[c0 + lane] : 0;
        int j = 0;
        for (; j + 1 < m; j += 2){
            int d0 = __shfl(dreg, j);
            int d1 = __shfl(dreg, j + 1);
            float e0 = lrelu_neg_exp(s1l + s12[d0 * NH + h]);
            float e1 = lrelu_neg_exp(s1l + s12[d1 * NH + h]);
            uint4 v0 = *(const uint4*)(h1 + (size_t)d0 * F1 + lane * 8);
            uint4 v1 = *(const uint4*)(h1 + (size_t)d1 * F1 + lane * 8);
            ded += e0 + e1;
            fma8(acc, v0, e0);
            fma8(acc, v1, e1);
        }
        if (j < m){
            int d0 = __shfl(dreg, j);
            float e0 = lrelu_neg_exp(s1l + s12[d0 * NH + h]);
            uint4 v0 = *(const uint4*)(h1 + (size_t)d0 * F1 + lane * 8);
            ded += e0;
            fma8(acc, v0, e0);
        }
    }
    const float inv = 1.f / (ded + EPSF);
    float o[8];
#pragma unroll
    for (int i = 0; i < 8; i++) o[i] = eluf(acc[i] * inv);
    uint4 ov;
    ov.x = bpack(o[0], o[1]); ov.y = bpack(o[2], o[3]);
    ov.z = bpack(o[4], o[5]); ov.w = bpack(o[6], o[7]);
    *(uint4*)(x1 + (size_t)n * F1 + lane * 8) = ov;
}

// ---------------- per-node attention scalars, layer 2 (bf16 h2) ----------------
__global__ void k_s2(const bf16* __restrict__ h2, const float* __restrict__ ao,
                     float* __restrict__ s21, float* __restrict__ s22){
    int n = blockIdx.x * 256 + threadIdx.x;
    if (n >= NN) return;
    const uint4* hp = (const uint4*)(h2 + (size_t)n * EMB);
    float d1 = 0.f, d2 = 0.f;
#pragma unroll
    for (int u = 0; u < 16; u++){
        uint4 v = hp[u];
        int j = u * 8;
        float f0 = b2f(v.x & 0xffffu), f1 = b2f(v.x >> 16);
        float f2 = b2f(v.y & 0xffffu), f3 = b2f(v.y >> 16);
        float f4 = b2f(v.z & 0xffffu), f5 = b2f(v.z >> 16);
        float f6 = b2f(v.w & 0xffffu), f7 = b2f(v.w >> 16);
        d1 += f0 * ao[j]     + f1 * ao[j + 1] + f2 * ao[j + 2] + f3 * ao[j + 3]
            + f4 * ao[j + 4] + f5 * ao[j + 5] + f6 * ao[j + 6] + f7 * ao[j + 7];
        d2 += f0 * ao[EMB + j]     + f1 * ao[EMB + j + 1] + f2 * ao[EMB + j + 2] + f3 * ao[EMB + j + 3]
            + f4 * ao[EMB + j + 4] + f5 * ao[EMB + j + 5] + f6 * ao[EMB + j + 6] + f7 * ao[EMB + j + 7];
    }
    s21[n] = d1;
    s22[n] = d2;
}

// ---------------- layer-2 aggregation: one WAVE per node, 4 edge-slots x 16 lanes ----------------
__global__ __launch_bounds__(256) void k_agg2(const bf16* __restrict__ h2,
                                              const float* __restrict__ s21,
                                              const float* __restrict__ s22,
                                              const int* __restrict__ rp,
                                              const int* __restrict__ sdst,
                                              float* __restrict__ den2,
                                              float* __restrict__ out0){
    const int t = threadIdx.x, lane = t & 63, w = t >> 6;
    const int n = blockIdx.x * 4 + w;
    const int slot = lane >> 4, fl = (lane & 15) * 8;
    const float s1v = s21[n];
    float acc[8] = {0.f,0.f,0.f,0.f,0.f,0.f,0.f,0.f};
    float ded = 0.f;
    const int start = rp[n], end = rp[n + 1];
    for (int c0 = start; c0 < end; c0 += 64){
        const int m = min(64, end - c0);
        int dreg = (lane < m) ? sdst[c0 + lane] : 0;
        for (int j = 0; j < m; j += 4){
            int idx = j + slot;
            if (idx < m){
                int d = __shfl(dreg, idx);
                float ee = lrelu_neg_exp(s1v + s22[d]);
                uint4 v = *(const uint4*)(h2 + (size_t)d * EMB + fl);
                ded += ee;
                fma8(acc, v, ee);
            }
        }
    }
    // reduce across the 4 slots
#pragma unroll
    for (int o = 16; o <= 32; o <<= 1){
        ded += __shfl_xor(ded, o);
#pragma unroll
        for (int i = 0; i < 8; i++) acc[i] += __shfl_xor(acc[i], o);
    }
    const float den = ded + EPSF;
    if (slot == 0){
        const float inv = 1.f / den;
        float4 o0, o1;
        o0.x = eluf(acc[0] * inv); o0.y = eluf(acc[1] * inv);
        o0.z = eluf(acc[2] * inv); o0.w = eluf(acc[3] * inv);
        o1.x = eluf(acc[4] * inv); o1.y = eluf(acc[5] * inv);
        o1.z = eluf(acc[6] * inv); o1.w = eluf(acc[7] * inv);
        float* op = out0 + (size_t)n * EMB + fl;
        *(float4*)op = o0;
        *(float4*)(op + 4) = o1;
        if (lane == 0) den2[n] = den;
    }
}

// ---------------- att_out in original edge order ----------------
__global__ void k_att(const int* __restrict__ src, const int* __restrict__ dst,
                      const float* __restrict__ s21, const float* __restrict__ s22,
                      const float* __restrict__ den2, float* __restrict__ outA){
    int e = blockIdx.x * 256 + threadIdx.x;
    if (e >= NE) return;
    int s = src[e], d = dst[e];
    float ee = lrelu_neg_exp(s21[s] + s22[d]);
    outA[e] = ee / den2[s];
}

__global__ void k_edgecopy(const int* __restrict__ ei, float* __restrict__ outE){
    int i = blockIdx.x * 256 + threadIdx.x;
    if (i < 2 * NE) outE[i] = (float)ei[i];
}

// ---------------- launch ----------------
extern "C" void kernel_launch(void* const* d_in, const int* in_sizes, int n_in,
                              void* d_out, int out_size, void* d_ws, size_t ws_size,
                              hipStream_t stream){
    const float* x  = (const float*)d_in[0];
    const int*   ei = (const int*)d_in[1];
    const float* W1 = (const float*)d_in[2];
    const float* a1 = (const float*)d_in[3];
    const float* Wo = (const float*)d_in[4];
    const float* ao = (const float*)d_in[5];
    float* out = (float*)d_out;
    const int* src = ei;
    const int* dst = ei + NE;

    char* w = (char*)d_ws;
    auto alloc = [&](size_t bytes) -> char* {
        char* p = w;
        w += (bytes + 255) & ~(size_t)255;
        return p;
    };
    bf16*  xb   = (bf16*) alloc((size_t)NN * FIN * 2);  // 25.6 MB
    bf16*  h1   = (bf16*) alloc((size_t)NN * F1 * 2);   // 51.2 MB
    bf16*  x1   = (bf16*) alloc((size_t)NN * F1 * 2);   // 51.2 MB
    float* s11  = (float*)alloc((size_t)NN * NH * 4);
    float* s12  = (float*)alloc((size_t)NN * NH * 4);
    float* s21  = (float*)alloc((size_t)NN * 4);
    float* s22  = (float*)alloc((size_t)NN * 4);
    float* den2 = (float*)alloc((size_t)NN * 4);
    int*   cnt2 = (int*)  alloc((size_t)2 * NN * 4);
    int*   rp   = (int*)  alloc((size_t)(NN + 1) * 4);
    int*   sdst = (int*)  alloc((size_t)NE * 4);
    int*   cnt = cnt2;
    int*   cur = cnt2 + NN;
    bf16* Bt1 = x1;                 // dead before k_agg1 writes x1
    bf16* WoT = (bf16*)s21;         // dead before k_s2 writes s21
    bf16* h2  = h1;                 // h1 dead after k_agg1

    // input conversion / weight transposes
    k_cvt_x<<<(NN * FIN / 8 + 255) / 256, 256, 0, stream>>>(x, xb);
    k_tw1  <<<(F1 * FIN + 255) / 256,     256, 0, stream>>>(W1, Bt1);
    k_tw2  <<<(EMB * F1 + 255) / 256,     256, 0, stream>>>(Wo, WoT);

    // CSR build
    k_zero   <<<(2 * NN + 255) / 256, 256, 0, stream>>>(cnt2, 2 * NN);
    k_count  <<<(NE + 255) / 256,     256, 0, stream>>>(src, cnt);
    k_scan   <<<1,                    256, 0, stream>>>(cnt, rp);
    k_scatter<<<(NE + 255) / 256,     256, 0, stream>>>(src, dst, rp, cur, sdst);

    // layer 1
    k_mgemm<FIN><<<dim3((NN + 127) / 128, F1 / 128), 256, 0, stream>>>(xb, Bt1, h1, F1);
    k_s1  <<<(NN * NH + 255) / 256, 256, 0, stream>>>(h1, a1, s11, s12);
    k_agg1<<<NN / 4, 256, 0, stream>>>(h1, s11, s12, rp, sdst, x1);

    // layer 2
    k_mgemm<F1><<<dim3((NN + 127) / 128, EMB / 128), 256, 0, stream>>>(x1, WoT, h2, EMB);
    k_s2  <<<(NN + 255) / 256, 256, 0, stream>>>(h2, ao, s21, s22);
    k_agg2<<<NN / 4, 256, 0, stream>>>(h2, s21, s22, rp, sdst, den2, out);

    // outputs 1 & 2
    k_att     <<<(NE + 255) / 256,     256, 0, stream>>>(src, dst, s21, s22, den2,
                                                         out + (size_t)NN * EMB + 2 * NE);
    k_edgecopy<<<(2 * NE + 255) / 256, 256, 0, stream>>>(ei, out + (size_t)NN * EMB);
}

// Round 5
// 468.068 us; speedup vs baseline: 1.8040x; 1.0049x over previous
//
#include <hip/hip_runtime.h>
#include <hip/hip_bf16.h>
#include <cstddef>

#define NN    50000
#define NE    800000
#define FIN   256
#define HID   64
#define NH    8
#define F1    512      // NH*HID
#define EMB   128
#define ALPHA 0.2f
#define EPSF  1e-16f

typedef __hip_bfloat16 bf16;
typedef __attribute__((ext_vector_type(8))) short short8;
typedef __attribute__((ext_vector_type(4))) float f32x4;

__device__ __forceinline__ float eluf(float x){ return x > 0.f ? x : expm1f(x); }
__device__ __forceinline__ float lrelu_neg_exp(float s){
    float lr = s > 0.f ? s : ALPHA * s;
    return __expf(-lr);
}
__device__ __forceinline__ float b2f(unsigned u){ return __uint_as_float(u << 16); }

// acc[0..7] += e * bf16x8(v)
__device__ __forceinline__ void fma8(float* acc, uint4 v, float e){
    acc[0] += e * __uint_as_float(v.x << 16);
    acc[1] += e * __uint_as_float(v.x & 0xffff0000u);
    acc[2] += e * __uint_as_float(v.y << 16);
    acc[3] += e * __uint_as_float(v.y & 0xffff0000u);
    acc[4] += e * __uint_as_float(v.z << 16);
    acc[5] += e * __uint_as_float(v.z & 0xffff0000u);
    acc[6] += e * __uint_as_float(v.w << 16);
    acc[7] += e * __uint_as_float(v.w & 0xffff0000u);
}
// pack two floats as bf16 pair (RNE)
__device__ __forceinline__ unsigned bpack(float a, float b){
    unsigned ua = __float_as_uint(a), ub = __float_as_uint(b);
    ua = (ua + 0x7fffu + ((ua >> 16) & 1)) >> 16;
    ub = (ub + 0x7fffu + ((ub >> 16) & 1)) >> 16;
    return (ua & 0xffffu) | (ub << 16);
}

// ---------------- input conversions ----------------
__global__ void k_cvt_x(const float* __restrict__ x, bf16* __restrict__ xb){
    int i = blockIdx.x * 256 + threadIdx.x;          // one thread = 8 elems
    if (i >= NN * FIN / 8) return;
    const float4* xp = (const float4*)(x + (size_t)i * 8);
    float4 v0 = xp[0], v1 = xp[1];
    uint4 o;
    o.x = bpack(v0.x, v0.y); o.y = bpack(v0.z, v0.w);
    o.z = bpack(v1.x, v1.y); o.w = bpack(v1.z, v1.w);
    *(uint4*)(xb + (size_t)i * 8) = o;
}

// Bt1[n][k] = W1[n>>6][k][n&63]   (512 x 256, bf16)
__global__ void k_tw1(const float* __restrict__ W1, bf16* __restrict__ Bt1){
    int i = blockIdx.x * 256 + threadIdx.x;
    if (i >= F1 * FIN) return;
    int n = i >> 8, k = i & 255;
    Bt1[i] = __float2bfloat16(W1[(size_t)(n >> 6) * FIN * HID + (size_t)k * HID + (n & 63)]);
}

// WoT[n][k] = Wo[k][n]   (128 x 512, bf16)
__global__ void k_tw2(const float* __restrict__ Wo, bf16* __restrict__ WoT){
    int i = blockIdx.x * 256 + threadIdx.x;
    if (i >= EMB * F1) return;
    int n = i >> 9, k = i & 511;
    WoT[i] = __float2bfloat16(Wo[(size_t)k * EMB + n]);
}

// ---------------- CSR build ----------------
__global__ void k_zero(int* p, int n){
    int i = blockIdx.x * 256 + threadIdx.x;
    if (i < n) p[i] = 0;
}

__global__ void k_count(const int* __restrict__ src, int* __restrict__ cnt){
    int e = blockIdx.x * 256 + threadIdx.x;
    if (e < NE) atomicAdd(&cnt[src[e]], 1);
}

__global__ __launch_bounds__(256) void k_scan(const int* __restrict__ cnt, int* __restrict__ rp){
    __shared__ int part[256];
    const int CH = (NN + 255) / 256;   // 196
    int t = threadIdx.x;
    int s = 0;
    for (int i = 0; i < CH; i++){
        int idx = t * CH + i;
        if (idx < NN) s += cnt[idx];
    }
    part[t] = s;
    __syncthreads();
    for (int o = 1; o < 256; o <<= 1){
        int v = (t >= o) ? part[t - o] : 0;
        __syncthreads();
        part[t] += v;
        __syncthreads();
    }
    int base = (t == 0) ? 0 : part[t - 1];
    for (int i = 0; i < CH; i++){
        int idx = t * CH + i;
        if (idx < NN){ rp[idx] = base; base += cnt[idx]; }
    }
    if (t == 255) rp[NN] = part[255];
}

__global__ void k_scatter(const int* __restrict__ src, const int* __restrict__ dst,
                          const int* __restrict__ rp, int* __restrict__ cur,
                          int* __restrict__ sdst){
    int e = blockIdx.x * 256 + threadIdx.x;
    if (e < NE){
        int s = src[e];
        int p = atomicAdd(&cur[s], 1);
        sdst[rp[s] + p] = dst[e];
    }
}

// ---------------- MFMA GEMM: C[M][N] = A[M][K] @ B^T[N][K], bf16 in/out ----------------
template<int K>
__global__ __launch_bounds__(256) void k_mgemm(const bf16* __restrict__ A,
                                               const bf16* __restrict__ B,
                                               bf16* __restrict__ C,
                                               int N){
    constexpr int LDT = 40;                     // bf16 elems per LDS row (80B, conflict-free)
    __shared__ __align__(16) bf16 As[128 * LDT];
    __shared__ __align__(16) bf16 Bs[128 * LDT];
    const int t = threadIdx.x;
    const int lane = t & 63, wid = t >> 6;
    const int m0 = blockIdx.x * 128, n0 = blockIdx.y * 128;
    const int r0 = t >> 2, u0 = t & 3;          // rows 0..63
    const int r1 = r0 + 64;                     // rows 64..127
    const int rb = (wid & 1) * 64, cb = (wid >> 1) * 64;
    const int fr = lane & 15, fk = (lane >> 4) * 8;

    f32x4 acc[4][4];
#pragma unroll
    for (int i = 0; i < 4; i++)
#pragma unroll
        for (int j = 0; j < 4; j++) acc[i][j] = (f32x4)(0.f);

    for (int k0 = 0; k0 < K; k0 += 32){
        const int ga0 = m0 + r0, ga1 = m0 + r1;
        uint4 av0 = (ga0 < NN) ? *(const uint4*)(A + (size_t)ga0 * K + k0 + u0 * 8)
                               : make_uint4(0, 0, 0, 0);
        uint4 av1 = (ga1 < NN) ? *(const uint4*)(A + (size_t)ga1 * K + k0 + u0 * 8)
                               : make_uint4(0, 0, 0, 0);
        uint4 bv0 = *(const uint4*)(B + (size_t)(n0 + r0) * K + k0 + u0 * 8);
        uint4 bv1 = *(const uint4*)(B + (size_t)(n0 + r1) * K + k0 + u0 * 8);
        __syncthreads();
        *(uint4*)(As + r0 * LDT + u0 * 8) = av0;
        *(uint4*)(As + r1 * LDT + u0 * 8) = av1;
        *(uint4*)(Bs + r0 * LDT + u0 * 8) = bv0;
        *(uint4*)(Bs + r1 * LDT + u0 * 8) = bv1;
        __syncthreads();
        short8 af[4], bf_[4];
#pragma unroll
        for (int i = 0; i < 4; i++){
            af[i]  = *(const short8*)(As + (rb + i * 16 + fr) * LDT + fk);
            bf_[i] = *(const short8*)(Bs + (cb + i * 16 + fr) * LDT + fk);
        }
#pragma unroll
        for (int i = 0; i < 4; i++)
#pragma unroll
            for (int j = 0; j < 4; j++)
                acc[i][j] = __builtin_amdgcn_mfma_f32_16x16x32_bf16(af[i], bf_[j], acc[i][j], 0, 0, 0);
    }
    const int crow = m0 + rb + (lane >> 4) * 4;
    const int ccol = n0 + cb + (lane & 15);
#pragma unroll
    for (int i = 0; i < 4; i++)
#pragma unroll
        for (int j = 0; j < 4; j++)
#pragma unroll
            for (int v = 0; v < 4; v++){
                int row = crow + i * 16 + v;
                if (row < NN)
                    C[(size_t)row * N + ccol + j * 16] = __float2bfloat16(acc[i][j][v]);
            }
}

// ---------------- per-node attention scalars, layer 1 ----------------
__global__ void k_s1(const bf16* __restrict__ h1, const float* __restrict__ a1,
                     float* __restrict__ s11, float* __restrict__ s12){
    int idx = blockIdx.x * 256 + threadIdx.x;
    if (idx >= NN * NH) return;
    int n = idx >> 3, h = idx & 7;
    const uint4* hp = (const uint4*)(h1 + (size_t)n * F1 + h * HID);
    const float* a  = a1 + (size_t)h * 2 * HID;
    float d1 = 0.f, d2 = 0.f;
#pragma unroll
    for (int u = 0; u < 8; u++){
        uint4 v = hp[u];
        int j = u * 8;
        float f0 = b2f(v.x & 0xffffu), f1 = b2f(v.x >> 16);
        float f2 = b2f(v.y & 0xffffu), f3 = b2f(v.y >> 16);
        float f4 = b2f(v.z & 0xffffu), f5 = b2f(v.z >> 16);
        float f6 = b2f(v.w & 0xffffu), f7 = b2f(v.w >> 16);
        d1 += f0 * a[j]     + f1 * a[j + 1] + f2 * a[j + 2] + f3 * a[j + 3]
            + f4 * a[j + 4] + f5 * a[j + 5] + f6 * a[j + 6] + f7 * a[j + 7];
        d2 += f0 * a[HID + j]     + f1 * a[HID + j + 1] + f2 * a[HID + j + 2] + f3 * a[HID + j + 3]
            + f4 * a[HID + j + 4] + f5 * a[HID + j + 5] + f6 * a[HID + j + 6] + f7 * a[HID + j + 7];
    }
    s11[idx] = d1;   // layout [n][h]
    s12[idx] = d2;
}

// ---------------- layer-1 aggregation: one WAVE per node, 8-edge x 8-head ee roles ----------
// Feature-owner role: lane owns features lane*8..lane*8+7 (head hf = lane>>3).
// ee-compute role (per 8-edge sub-chunk): lane computes ee for edge (lane>>3), head (lane&7).
__global__ __launch_bounds__(256) void k_agg1(const bf16* __restrict__ h1,
                                              const float* __restrict__ s11,
                                              const float* __restrict__ s12,
                                              const int* __restrict__ rp,
                                              const int* __restrict__ sdst,
                                              bf16* __restrict__ x1){
    const int t = threadIdx.x, lane = t & 63, w = t >> 6;
    const int n = blockIdx.x * 4 + w;
    const int ha = lane & 7;        // head for ee-compute role
    const int hf = lane >> 3;       // head of owned features
    const float s1a = s11[n * NH + ha];
    float acc[8] = {0.f,0.f,0.f,0.f,0.f,0.f,0.f,0.f};
    float dedp = 0.f;
    const int start = rp[n], end = rp[n + 1];
    const bf16* __restrict__ h1l = h1 + (size_t)lane * 8;   // lane-fixed base
    for (int c0 = start; c0 < end; c0 += 64){
        const int m = min(64, end - c0);
        int dreg = (lane < m) ? sdst[c0 + lane] : 0;
        const int full = m & ~7;
        for (int sc = 0; sc < full; sc += 8){
            int de = __shfl(dreg, sc + hf);             // edge sc+(lane>>3)
            float ev = lrelu_neg_exp(s1a + s12[de * NH + ha]);
            dedp += ev;
#pragma unroll
            for (int j = 0; j < 8; j++){
                int   dj = __shfl(dreg, sc + j);
                float ej = __shfl(ev, j * 8 + hf);
                uint4 v = *(const uint4*)(h1l + (size_t)dj * F1);
                fma8(acc, v, ej);
            }
        }
        if (full < m){
            int eloc = full + hf;                       // <= 63
            int de = __shfl(dreg, eloc);
            float ev = (eloc < m) ? lrelu_neg_exp(s1a + s12[de * NH + ha]) : 0.f;
            dedp += ev;
            const int mm = m - full;
            for (int j = 0; j < mm; j++){
                int   dj = __shfl(dreg, full + j);
                float ej = __shfl(ev, j * 8 + hf);
                uint4 v = *(const uint4*)(h1l + (size_t)dj * F1);
                fma8(acc, v, ej);
            }
        }
    }
    // reduce dedp over the 8 edge-slots (lane bits 3..5); lane l then holds ded[l&7]
    dedp += __shfl_xor(dedp, 8);
    dedp += __shfl_xor(dedp, 16);
    dedp += __shfl_xor(dedp, 32);
    float ded = __shfl(dedp, hf);                       // ded for my feature head
    const float inv = 1.f / (ded + EPSF);
    float o[8];
#pragma unroll
    for (int i = 0; i < 8; i++) o[i] = eluf(acc[i] * inv);
    uint4 ov;
    ov.x = bpack(o[0], o[1]); ov.y = bpack(o[2], o[3]);
    ov.z = bpack(o[4], o[5]); ov.w = bpack(o[6], o[7]);
    *(uint4*)(x1 + (size_t)n * F1 + lane * 8) = ov;
}

// ---------------- per-node attention scalars, layer 2 (bf16 h2) ----------------
__global__ void k_s2(const bf16* __restrict__ h2, const float* __restrict__ ao,
                     float* __restrict__ s21, float* __restrict__ s22){
    int n = blockIdx.x * 256 + threadIdx.x;
    if (n >= NN) return;
    const uint4* hp = (const uint4*)(h2 + (size_t)n * EMB);
    float d1 = 0.f, d2 = 0.f;
#pragma unroll
    for (int u = 0; u < 16; u++){
        uint4 v = hp[u];
        int j = u * 8;
        float f0 = b2f(v.x & 0xffffu), f1 = b2f(v.x >> 16);
        float f2 = b2f(v.y & 0xffffu), f3 = b2f(v.y >> 16);
        float f4 = b2f(v.z & 0xffffu), f5 = b2f(v.z >> 16);
        float f6 = b2f(v.w & 0xffffu), f7 = b2f(v.w >> 16);
        d1 += f0 * ao[j]     + f1 * ao[j + 1] + f2 * ao[j + 2] + f3 * ao[j + 3]
            + f4 * ao[j + 4] + f5 * ao[j + 5] + f6 * ao[j + 6] + f7 * ao[j + 7];
        d2 += f0 * ao[EMB + j]     + f1 * ao[EMB + j + 1] + f2 * ao[EMB + j + 2] + f3 * ao[EMB + j + 3]
            + f4 * ao[EMB + j + 4] + f5 * ao[EMB + j + 5] + f6 * ao[EMB + j + 6] + f7 * ao[EMB + j + 7];
    }
    s21[n] = d1;
    s22[n] = d2;
}

// ---------------- layer-2 aggregation: one WAVE per node, 4 edge-slots x 16 lanes ----------------
__global__ __launch_bounds__(256) void k_agg2(const bf16* __restrict__ h2,
                                              const float* __restrict__ s21,
                                              const float* __restrict__ s22,
                                              const int* __restrict__ rp,
                                              const int* __restrict__ sdst,
                                              float* __restrict__ den2,
                                              float* __restrict__ out0){
    const int t = threadIdx.x, lane = t & 63, w = t >> 6;
    const int n = blockIdx.x * 4 + w;
    const int slot = lane >> 4, fl = (lane & 15) * 8;
    const float s1v = s21[n];
    float acc[8] = {0.f,0.f,0.f,0.f,0.f,0.f,0.f,0.f};
    float ded = 0.f;
    const int start = rp[n], end = rp[n + 1];
    for (int c0 = start; c0 < end; c0 += 64){
        const int m = min(64, end - c0);
        int dreg = (lane < m) ? sdst[c0 + lane] : 0;
        for (int j = 0; j < m; j += 4){
            int idx = j + slot;
            if (idx < m){
                int d = __shfl(dreg, idx);
                float ee = lrelu_neg_exp(s1v + s22[d]);
                uint4 v = *(const uint4*)(h2 + (size_t)d * EMB + fl);
                ded += ee;
                fma8(acc, v, ee);
            }
        }
    }
#pragma unroll
    for (int o = 16; o <= 32; o <<= 1){
        ded += __shfl_xor(ded, o);
#pragma unroll
        for (int i = 0; i < 8; i++) acc[i] += __shfl_xor(acc[i], o);
    }
    const float den = ded + EPSF;
    if (slot == 0){
        const float inv = 1.f / den;
        float4 o0, o1;
        o0.x = eluf(acc[0] * inv); o0.y = eluf(acc[1] * inv);
        o0.z = eluf(acc[2] * inv); o0.w = eluf(acc[3] * inv);
        o1.x = eluf(acc[4] * inv); o1.y = eluf(acc[5] * inv);
        o1.z = eluf(acc[6] * inv); o1.w = eluf(acc[7] * inv);
        float* op = out0 + (size_t)n * EMB + fl;
        *(float4*)op = o0;
        *(float4*)(op + 4) = o1;
        if (lane == 0) den2[n] = den;
    }
}

// ---------------- fused: edge_index copy + att_out (original edge order) ----------------
__global__ void k_att_edge(const int* __restrict__ ei,
                           const float* __restrict__ s21, const float* __restrict__ s22,
                           const float* __restrict__ den2,
                           float* __restrict__ outE, float* __restrict__ outA){
    int i = blockIdx.x * 256 + threadIdx.x;
    if (i < 2 * NE) outE[i] = (float)ei[i];
    if (i < NE){
        int s = ei[i], d = ei[NE + i];
        float ee = lrelu_neg_exp(s21[s] + s22[d]);
        outA[i] = ee / den2[s];
    }
}

// ---------------- launch ----------------
extern "C" void kernel_launch(void* const* d_in, const int* in_sizes, int n_in,
                              void* d_out, int out_size, void* d_ws, size_t ws_size,
                              hipStream_t stream){
    const float* x  = (const float*)d_in[0];
    const int*   ei = (const int*)d_in[1];
    const float* W1 = (const float*)d_in[2];
    const float* a1 = (const float*)d_in[3];
    const float* Wo = (const float*)d_in[4];
    const float* ao = (const float*)d_in[5];
    float* out = (float*)d_out;
    const int* src = ei;
    const int* dst = ei + NE;

    char* w = (char*)d_ws;
    auto alloc = [&](size_t bytes) -> char* {
        char* p = w;
        w += (bytes + 255) & ~(size_t)255;
        return p;
    };
    bf16*  xb   = (bf16*) alloc((size_t)NN * FIN * 2);  // 25.6 MB
    bf16*  h1   = (bf16*) alloc((size_t)NN * F1 * 2);   // 51.2 MB
    bf16*  x1   = (bf16*) alloc((size_t)NN * F1 * 2);   // 51.2 MB
    float* s11  = (float*)alloc((size_t)NN * NH * 4);
    float* s12  = (float*)alloc((size_t)NN * NH * 4);
    float* s21  = (float*)alloc((size_t)NN * 4);
    float* s22  = (float*)alloc((size_t)NN * 4);
    float* den2 = (float*)alloc((size_t)NN * 4);
    int*   cnt2 = (int*)  alloc((size_t)2 * NN * 4);
    int*   rp   = (int*)  alloc((size_t)(NN + 1) * 4);
    int*   sdst = (int*)  alloc((size_t)NE * 4);
    int*   cnt = cnt2;
    int*   cur = cnt2 + NN;
    bf16* Bt1 = x1;                 // dead before k_agg1 writes x1
    bf16* WoT = (bf16*)s21;         // dead before k_s2 writes s21
    bf16* h2  = h1;                 // h1 dead after k_agg1

    // input conversion / weight transposes
    k_cvt_x<<<(NN * FIN / 8 + 255) / 256, 256, 0, stream>>>(x, xb);
    k_tw1  <<<(F1 * FIN + 255) / 256,     256, 0, stream>>>(W1, Bt1);
    k_tw2  <<<(EMB * F1 + 255) / 256,     256, 0, stream>>>(Wo, WoT);

    // CSR build
    k_zero   <<<(2 * NN + 255) / 256, 256, 0, stream>>>(cnt2, 2 * NN);
    k_count  <<<(NE + 255) / 256,     256, 0, stream>>>(src, cnt);
    k_scan   <<<1,                    256, 0, stream>>>(cnt, rp);
    k_scatter<<<(NE + 255) / 256,     256, 0, stream>>>(src, dst, rp, cur, sdst);

    // layer 1
    k_mgemm<FIN><<<dim3((NN + 127) / 128, F1 / 128), 256, 0, stream>>>(xb, Bt1, h1, F1);
    k_s1  <<<(NN * NH + 255) / 256, 256, 0, stream>>>(h1, a1, s11, s12);
    k_agg1<<<NN / 4, 256, 0, stream>>>(h1, s11, s12, rp, sdst, x1);

    // layer 2
    k_mgemm<F1><<<dim3((NN + 127) / 128, EMB / 128), 256, 0, stream>>>(x1, WoT, h2, EMB);
    k_s2  <<<(NN + 255) / 256, 256, 0, stream>>>(h2, ao, s21, s22);
    k_agg2<<<NN / 4, 256, 0, stream>>>(h2, s21, s22, rp, sdst, den2, out);

    // outputs 1 & 2 (fused)
    k_att_edge<<<(2 * NE + 255) / 256, 256, 0, stream>>>(ei, s21, s22, den2,
                                                         out + (size_t)NN * EMB,
                                                         out + (size_t)NN * EMB + 2 * NE);
}

// Round 6
// 422.399 us; speedup vs baseline: 1.9991x; 1.1081x over previous
//
#include <hip/hip_runtime.h>
#include <hip/hip_bf16.h>
#include <cstddef>

#define NN    50000
#define NE    800000
#define FIN   256
#define HID   64
#define NH    8
#define F1    512      // NH*HID
#define EMB   128
#define ALPHA 0.2f
#define EPSF  1e-16f

typedef __hip_bfloat16 bf16;
typedef __attribute__((ext_vector_type(8))) short short8;
typedef __attribute__((ext_vector_type(4))) float f32x4;
typedef __attribute__((ext_vector_type(2))) float f32x2;

__device__ __forceinline__ float eluf(float x){ return x > 0.f ? x : expm1f(x); }
__device__ __forceinline__ float lrelu_neg_exp(float s){
    float lr = s > 0.f ? s : ALPHA * s;
    return __expf(-lr);
}
__device__ __forceinline__ float b2f(unsigned u){ return __uint_as_float(u << 16); }

// acc[0..7] += e * fp8x8(q)   (OCP e4m3 hardware decode)
__device__ __forceinline__ void fma8q(float* acc, uint2 q, float e){
    f32x2 p0 = __builtin_amdgcn_cvt_pk_f32_fp8(q.x, false);
    f32x2 p1 = __builtin_amdgcn_cvt_pk_f32_fp8(q.x, true);
    f32x2 p2 = __builtin_amdgcn_cvt_pk_f32_fp8(q.y, false);
    f32x2 p3 = __builtin_amdgcn_cvt_pk_f32_fp8(q.y, true);
    acc[0] += e * p0[0]; acc[1] += e * p0[1];
    acc[2] += e * p1[0]; acc[3] += e * p1[1];
    acc[4] += e * p2[0]; acc[5] += e * p2[1];
    acc[6] += e * p3[0]; acc[7] += e * p3[1];
}
// pack two floats as bf16 pair (RNE)
__device__ __forceinline__ unsigned bpack(float a, float b){
    unsigned ua = __float_as_uint(a), ub = __float_as_uint(b);
    ua = (ua + 0x7fffu + ((ua >> 16) & 1)) >> 16;
    ub = (ub + 0x7fffu + ((ub >> 16) & 1)) >> 16;
    return (ua & 0xffffu) | (ub << 16);
}

// ---------------- input conversions ----------------
__global__ void k_cvt_x(const float* __restrict__ x, bf16* __restrict__ xb){
    int i = blockIdx.x * 256 + threadIdx.x;          // one thread = 8 elems
    if (i >= NN * FIN / 8) return;
    const float4* xp = (const float4*)(x + (size_t)i * 8);
    float4 v0 = xp[0], v1 = xp[1];
    uint4 o;
    o.x = bpack(v0.x, v0.y); o.y = bpack(v0.z, v0.w);
    o.z = bpack(v1.x, v1.y); o.w = bpack(v1.z, v1.w);
    *(uint4*)(xb + (size_t)i * 8) = o;
}

// bf16[8] -> fp8 e4m3[8] (HW encode), one thread = 8 elems
__global__ void k_q8(const bf16* __restrict__ in, unsigned char* __restrict__ out, int n8){
    int i = blockIdx.x * 256 + threadIdx.x;
    if (i >= n8) return;
    uint4 v = *(const uint4*)(in + (size_t)i * 8);
    float f0 = b2f(v.x & 0xffffu), f1 = b2f(v.x >> 16);
    float f2 = b2f(v.y & 0xffffu), f3 = b2f(v.y >> 16);
    float f4 = b2f(v.z & 0xffffu), f5 = b2f(v.z >> 16);
    float f6 = b2f(v.w & 0xffffu), f7 = b2f(v.w >> 16);
    unsigned lo = 0, hi = 0;
    lo = __builtin_amdgcn_cvt_pk_fp8_f32(f0, f1, lo, false);
    lo = __builtin_amdgcn_cvt_pk_fp8_f32(f2, f3, lo, true);
    hi = __builtin_amdgcn_cvt_pk_fp8_f32(f4, f5, hi, false);
    hi = __builtin_amdgcn_cvt_pk_fp8_f32(f6, f7, hi, true);
    uint2 o; o.x = lo; o.y = hi;
    *(uint2*)(out + (size_t)i * 8) = o;
}

// Bt1[n][k] = W1[n>>6][k][n&63]   (512 x 256, bf16)
__global__ void k_tw1(const float* __restrict__ W1, bf16* __restrict__ Bt1){
    int i = blockIdx.x * 256 + threadIdx.x;
    if (i >= F1 * FIN) return;
    int n = i >> 8, k = i & 255;
    Bt1[i] = __float2bfloat16(W1[(size_t)(n >> 6) * FIN * HID + (size_t)k * HID + (n & 63)]);
}

// WoT[n][k] = Wo[k][n]   (128 x 512, bf16)
__global__ void k_tw2(const float* __restrict__ Wo, bf16* __restrict__ WoT){
    int i = blockIdx.x * 256 + threadIdx.x;
    if (i >= EMB * F1) return;
    int n = i >> 9, k = i & 511;
    WoT[i] = __float2bfloat16(Wo[(size_t)k * EMB + n]);
}

// ---------------- CSR build ----------------
__global__ void k_zero(int* p, int n){
    int i = blockIdx.x * 256 + threadIdx.x;
    if (i < n) p[i] = 0;
}

__global__ void k_count(const int* __restrict__ src, int* __restrict__ cnt){
    int e = blockIdx.x * 256 + threadIdx.x;
    if (e < NE) atomicAdd(&cnt[src[e]], 1);
}

__global__ __launch_bounds__(256) void k_scan(const int* __restrict__ cnt, int* __restrict__ rp){
    __shared__ int part[256];
    const int CH = (NN + 255) / 256;   // 196
    int t = threadIdx.x;
    int s = 0;
    for (int i = 0; i < CH; i++){
        int idx = t * CH + i;
        if (idx < NN) s += cnt[idx];
    }
    part[t] = s;
    __syncthreads();
    for (int o = 1; o < 256; o <<= 1){
        int v = (t >= o) ? part[t - o] : 0;
        __syncthreads();
        part[t] += v;
        __syncthreads();
    }
    int base = (t == 0) ? 0 : part[t - 1];
    for (int i = 0; i < CH; i++){
        int idx = t * CH + i;
        if (idx < NN){ rp[idx] = base; base += cnt[idx]; }
    }
    if (t == 255) rp[NN] = part[255];
}

__global__ void k_scatter(const int* __restrict__ src, const int* __restrict__ dst,
                          const int* __restrict__ rp, int* __restrict__ cur,
                          int* __restrict__ sdst){
    int e = blockIdx.x * 256 + threadIdx.x;
    if (e < NE){
        int s = src[e];
        int p = atomicAdd(&cur[s], 1);
        sdst[rp[s] + p] = dst[e];
    }
}

// ---------------- MFMA GEMM: C[M][N] = A[M][K] @ B^T[N][K], bf16 in/out ----------------
template<int K>
__global__ __launch_bounds__(256) void k_mgemm(const bf16* __restrict__ A,
                                               const bf16* __restrict__ B,
                                               bf16* __restrict__ C,
                                               int N){
    constexpr int LDT = 40;                     // bf16 elems per LDS row (80B, conflict-free)
    __shared__ __align__(16) bf16 As[128 * LDT];
    __shared__ __align__(16) bf16 Bs[128 * LDT];
    const int t = threadIdx.x;
    const int lane = t & 63, wid = t >> 6;
    const int m0 = blockIdx.x * 128, n0 = blockIdx.y * 128;
    const int r0 = t >> 2, u0 = t & 3;          // rows 0..63
    const int r1 = r0 + 64;                     // rows 64..127
    const int rb = (wid & 1) * 64, cb = (wid >> 1) * 64;
    const int fr = lane & 15, fk = (lane >> 4) * 8;

    f32x4 acc[4][4];
#pragma unroll
    for (int i = 0; i < 4; i++)
#pragma unroll
        for (int j = 0; j < 4; j++) acc[i][j] = (f32x4)(0.f);

    for (int k0 = 0; k0 < K; k0 += 32){
        const int ga0 = m0 + r0, ga1 = m0 + r1;
        uint4 av0 = (ga0 < NN) ? *(const uint4*)(A + (size_t)ga0 * K + k0 + u0 * 8)
                               : make_uint4(0, 0, 0, 0);
        uint4 av1 = (ga1 < NN) ? *(const uint4*)(A + (size_t)ga1 * K + k0 + u0 * 8)
                               : make_uint4(0, 0, 0, 0);
        uint4 bv0 = *(const uint4*)(B + (size_t)(n0 + r0) * K + k0 + u0 * 8);
        uint4 bv1 = *(const uint4*)(B + (size_t)(n0 + r1) * K + k0 + u0 * 8);
        __syncthreads();
        *(uint4*)(As + r0 * LDT + u0 * 8) = av0;
        *(uint4*)(As + r1 * LDT + u0 * 8) = av1;
        *(uint4*)(Bs + r0 * LDT + u0 * 8) = bv0;
        *(uint4*)(Bs + r1 * LDT + u0 * 8) = bv1;
        __syncthreads();
        short8 af[4], bf_[4];
#pragma unroll
        for (int i = 0; i < 4; i++){
            af[i]  = *(const short8*)(As + (rb + i * 16 + fr) * LDT + fk);
            bf_[i] = *(const short8*)(Bs + (cb + i * 16 + fr) * LDT + fk);
        }
#pragma unroll
        for (int i = 0; i < 4; i++)
#pragma unroll
            for (int j = 0; j < 4; j++)
                acc[i][j] = __builtin_amdgcn_mfma_f32_16x16x32_bf16(af[i], bf_[j], acc[i][j], 0, 0, 0);
    }
    const int crow = m0 + rb + (lane >> 4) * 4;
    const int ccol = n0 + cb + (lane & 15);
#pragma unroll
    for (int i = 0; i < 4; i++)
#pragma unroll
        for (int j = 0; j < 4; j++)
#pragma unroll
            for (int v = 0; v < 4; v++){
                int row = crow + i * 16 + v;
                if (row < NN)
                    C[(size_t)row * N + ccol + j * 16] = __float2bfloat16(acc[i][j][v]);
            }
}

// ---------------- per-node attention scalars, layer 1 ----------------
__global__ void k_s1(const bf16* __restrict__ h1, const float* __restrict__ a1,
                     float* __restrict__ s11, float* __restrict__ s12){
    int idx = blockIdx.x * 256 + threadIdx.x;
    if (idx >= NN * NH) return;
    int n = idx >> 3, h = idx & 7;
    const uint4* hp = (const uint4*)(h1 + (size_t)n * F1 + h * HID);
    const float* a  = a1 + (size_t)h * 2 * HID;
    float d1 = 0.f, d2 = 0.f;
#pragma unroll
    for (int u = 0; u < 8; u++){
        uint4 v = hp[u];
        int j = u * 8;
        float f0 = b2f(v.x & 0xffffu), f1 = b2f(v.x >> 16);
        float f2 = b2f(v.y & 0xffffu), f3 = b2f(v.y >> 16);
        float f4 = b2f(v.z & 0xffffu), f5 = b2f(v.z >> 16);
        float f6 = b2f(v.w & 0xffffu), f7 = b2f(v.w >> 16);
        d1 += f0 * a[j]     + f1 * a[j + 1] + f2 * a[j + 2] + f3 * a[j + 3]
            + f4 * a[j + 4] + f5 * a[j + 5] + f6 * a[j + 6] + f7 * a[j + 7];
        d2 += f0 * a[HID + j]     + f1 * a[HID + j + 1] + f2 * a[HID + j + 2] + f3 * a[HID + j + 3]
            + f4 * a[HID + j + 4] + f5 * a[HID + j + 5] + f6 * a[HID + j + 6] + f7 * a[HID + j + 7];
    }
    s11[idx] = d1;   // layout [n][h]
    s12[idx] = d2;
}

// ---------------- layer-1 aggregation: one WAVE per node, fp8 gather payload ----------
__global__ __launch_bounds__(256) void k_agg1(const unsigned char* __restrict__ h1q,
                                              const float* __restrict__ s11,
                                              const float* __restrict__ s12,
                                              const int* __restrict__ rp,
                                              const int* __restrict__ sdst,
                                              bf16* __restrict__ x1){
    const int t = threadIdx.x, lane = t & 63, w = t >> 6;
    const int n = blockIdx.x * 4 + w;
    const int ha = lane & 7;        // head for ee-compute role
    const int hf = lane >> 3;       // head of owned features
    const float s1a = s11[n * NH + ha];
    float acc[8] = {0.f,0.f,0.f,0.f,0.f,0.f,0.f,0.f};
    float dedp = 0.f;
    const int start = rp[n], end = rp[n + 1];
    const unsigned char* __restrict__ h1l = h1q + (size_t)lane * 8;   // lane-fixed base
    for (int c0 = start; c0 < end; c0 += 64){
        const int m = min(64, end - c0);
        int dreg = (lane < m) ? sdst[c0 + lane] : 0;
        const int full = m & ~7;
        for (int sc = 0; sc < full; sc += 8){
            int de = __shfl(dreg, sc + hf);             // edge sc+(lane>>3)
            float ev = lrelu_neg_exp(s1a + s12[de * NH + ha]);
            dedp += ev;
#pragma unroll
            for (int j = 0; j < 8; j++){
                int   dj = __shfl(dreg, sc + j);
                float ej = __shfl(ev, j * 8 + hf);
                uint2 q = *(const uint2*)(h1l + (size_t)dj * F1);
                fma8q(acc, q, ej);
            }
        }
        if (full < m){
            int eloc = full + hf;                       // <= 63
            int de = __shfl(dreg, eloc);
            float ev = (eloc < m) ? lrelu_neg_exp(s1a + s12[de * NH + ha]) : 0.f;
            dedp += ev;
            const int mm = m - full;
            for (int j = 0; j < mm; j++){
                int   dj = __shfl(dreg, full + j);
                float ej = __shfl(ev, j * 8 + hf);
                uint2 q = *(const uint2*)(h1l + (size_t)dj * F1);
                fma8q(acc, q, ej);
            }
        }
    }
    // reduce dedp over the 8 edge-slots (lane bits 3..5); lane l then holds ded[l&7]
    dedp += __shfl_xor(dedp, 8);
    dedp += __shfl_xor(dedp, 16);
    dedp += __shfl_xor(dedp, 32);
    float ded = __shfl(dedp, hf);                       // ded for my feature head
    const float inv = 1.f / (ded + EPSF);
    float o[8];
#pragma unroll
    for (int i = 0; i < 8; i++) o[i] = eluf(acc[i] * inv);
    uint4 ov;
    ov.x = bpack(o[0], o[1]); ov.y = bpack(o[2], o[3]);
    ov.z = bpack(o[4], o[5]); ov.w = bpack(o[6], o[7]);
    *(uint4*)(x1 + (size_t)n * F1 + lane * 8) = ov;
}

// ---------------- per-node attention scalars, layer 2 (bf16 h2) ----------------
__global__ void k_s2(const bf16* __restrict__ h2, const float* __restrict__ ao,
                     float* __restrict__ s21, float* __restrict__ s22){
    int n = blockIdx.x * 256 + threadIdx.x;
    if (n >= NN) return;
    const uint4* hp = (const uint4*)(h2 + (size_t)n * EMB);
    float d1 = 0.f, d2 = 0.f;
#pragma unroll
    for (int u = 0; u < 16; u++){
        uint4 v = hp[u];
        int j = u * 8;
        float f0 = b2f(v.x & 0xffffu), f1 = b2f(v.x >> 16);
        float f2 = b2f(v.y & 0xffffu), f3 = b2f(v.y >> 16);
        float f4 = b2f(v.z & 0xffffu), f5 = b2f(v.z >> 16);
        float f6 = b2f(v.w & 0xffffu), f7 = b2f(v.w >> 16);
        d1 += f0 * ao[j]     + f1 * ao[j + 1] + f2 * ao[j + 2] + f3 * ao[j + 3]
            + f4 * ao[j + 4] + f5 * ao[j + 5] + f6 * ao[j + 6] + f7 * ao[j + 7];
        d2 += f0 * ao[EMB + j]     + f1 * ao[EMB + j + 1] + f2 * ao[EMB + j + 2] + f3 * ao[EMB + j + 3]
            + f4 * ao[EMB + j + 4] + f5 * ao[EMB + j + 5] + f6 * ao[EMB + j + 6] + f7 * ao[EMB + j + 7];
    }
    s21[n] = d1;
    s22[n] = d2;
}

// ---------------- layer-2 aggregation: one WAVE per node, fp8 payload ----------------
__global__ __launch_bounds__(256) void k_agg2(const unsigned char* __restrict__ h2q,
                                              const float* __restrict__ s21,
                                              const float* __restrict__ s22,
                                              const int* __restrict__ rp,
                                              const int* __restrict__ sdst,
                                              float* __restrict__ den2,
                                              float* __restrict__ out0){
    const int t = threadIdx.x, lane = t & 63, w = t >> 6;
    const int n = blockIdx.x * 4 + w;
    const int slot = lane >> 4, fl = (lane & 15) * 8;
    const float s1v = s21[n];
    float acc[8] = {0.f,0.f,0.f,0.f,0.f,0.f,0.f,0.f};
    float dedp = 0.f;
    const int start = rp[n], end = rp[n + 1];
    const unsigned char* __restrict__ h2l = h2q + fl;
    for (int c0 = start; c0 < end; c0 += 64){
        const int m = min(64, end - c0);
        int dreg = (lane < m) ? sdst[c0 + lane] : 0;
        // each lane computes ee for ITS edge once
        float ev = (lane < m) ? lrelu_neg_exp(s1v + s22[dreg]) : 0.f;
        dedp += ev;
        for (int j = slot; j < m; j += 4){
            int   d = __shfl(dreg, j);
            float e = __shfl(ev, j);
            uint2 q = *(const uint2*)(h2l + (size_t)d * EMB);
            fma8q(acc, q, e);
        }
    }
    // denominator: full 64-lane reduction
#pragma unroll
    for (int o = 1; o <= 32; o <<= 1) dedp += __shfl_xor(dedp, o);
    // acc: reduce across the 4 slots
#pragma unroll
    for (int o = 16; o <= 32; o <<= 1)
#pragma unroll
        for (int i = 0; i < 8; i++) acc[i] += __shfl_xor(acc[i], o);
    const float den = dedp + EPSF;
    if (slot == 0){
        const float inv = 1.f / den;
        float4 o0, o1;
        o0.x = eluf(acc[0] * inv); o0.y = eluf(acc[1] * inv);
        o0.z = eluf(acc[2] * inv); o0.w = eluf(acc[3] * inv);
        o1.x = eluf(acc[4] * inv); o1.y = eluf(acc[5] * inv);
        o1.z = eluf(acc[6] * inv); o1.w = eluf(acc[7] * inv);
        float* op = out0 + (size_t)n * EMB + fl;
        *(float4*)op = o0;
        *(float4*)(op + 4) = o1;
        if (lane == 0) den2[n] = den;
    }
}

// ---------------- fused: edge_index copy + att_out (original edge order) ----------------
__global__ void k_att_edge(const int* __restrict__ ei,
                           const float* __restrict__ s21, const float* __restrict__ s22,
                           const float* __restrict__ den2,
                           float* __restrict__ outE, float* __restrict__ outA){
    int i = blockIdx.x * 256 + threadIdx.x;
    if (i < 2 * NE) outE[i] = (float)ei[i];
    if (i < NE){
        int s = ei[i], d = ei[NE + i];
        float ee = lrelu_neg_exp(s21[s] + s22[d]);
        outA[i] = ee / den2[s];
    }
}

// ---------------- launch ----------------
extern "C" void kernel_launch(void* const* d_in, const int* in_sizes, int n_in,
                              void* d_out, int out_size, void* d_ws, size_t ws_size,
                              hipStream_t stream){
    const float* x  = (const float*)d_in[0];
    const int*   ei = (const int*)d_in[1];
    const float* W1 = (const float*)d_in[2];
    const float* a1 = (const float*)d_in[3];
    const float* Wo = (const float*)d_in[4];
    const float* ao = (const float*)d_in[5];
    float* out = (float*)d_out;
    const int* src = ei;
    const int* dst = ei + NE;

    char* w = (char*)d_ws;
    auto alloc = [&](size_t bytes) -> char* {
        char* p = w;
        w += (bytes + 255) & ~(size_t)255;
        return p;
    };
    bf16*  xb   = (bf16*) alloc((size_t)NN * FIN * 2);  // 25.6 MB
    bf16*  h1   = (bf16*) alloc((size_t)NN * F1 * 2);   // 51.2 MB
    bf16*  x1   = (bf16*) alloc((size_t)NN * F1 * 2);   // 51.2 MB
    float* s11  = (float*)alloc((size_t)NN * NH * 4);
    float* s12  = (float*)alloc((size_t)NN * NH * 4);
    float* s21  = (float*)alloc((size_t)NN * 4);
    float* s22  = (float*)alloc((size_t)NN * 4);
    float* den2 = (float*)alloc((size_t)NN * 4);
    int*   cnt2 = (int*)  alloc((size_t)2 * NN * 4);
    int*   rp   = (int*)  alloc((size_t)(NN + 1) * 4);
    int*   sdst = (int*)  alloc((size_t)NE * 4);
    int*   cnt = cnt2;
    int*   cur = cnt2 + NN;
    // lifetime-disjoint aliases:
    bf16* Bt1 = x1;                         // dead before k_agg1 writes x1
    bf16* WoT = (bf16*)s21;                 // dead before k_s2 writes s21
    bf16* h2  = h1;                         // h1 dead after k_agg1
    unsigned char* h1q = (unsigned char*)xb;  // xb dead after gemm1 (25.6 MB exact)
    unsigned char* h2q = (unsigned char*)x1;  // x1 dead after gemm2 (needs 6.4 MB)

    // input conversion / weight transposes
    k_cvt_x<<<(NN * FIN / 8 + 255) / 256, 256, 0, stream>>>(x, xb);
    k_tw1  <<<(F1 * FIN + 255) / 256,     256, 0, stream>>>(W1, Bt1);
    k_tw2  <<<(EMB * F1 + 255) / 256,     256, 0, stream>>>(Wo, WoT);

    // CSR build
    k_zero   <<<(2 * NN + 255) / 256, 256, 0, stream>>>(cnt2, 2 * NN);
    k_count  <<<(NE + 255) / 256,     256, 0, stream>>>(src, cnt);
    k_scan   <<<1,                    256, 0, stream>>>(cnt, rp);
    k_scatter<<<(NE + 255) / 256,     256, 0, stream>>>(src, dst, rp, cur, sdst);

    // layer 1
    k_mgemm<FIN><<<dim3((NN + 127) / 128, F1 / 128), 256, 0, stream>>>(xb, Bt1, h1, F1);
    k_q8  <<<(NN * F1 / 8 + 255) / 256, 256, 0, stream>>>(h1, h1q, NN * F1 / 8);
    k_s1  <<<(NN * NH + 255) / 256, 256, 0, stream>>>(h1, a1, s11, s12);
    k_agg1<<<NN / 4, 256, 0, stream>>>(h1q, s11, s12, rp, sdst, x1);

    // layer 2
    k_mgemm<F1><<<dim3((NN + 127) / 128, EMB / 128), 256, 0, stream>>>(x1, WoT, h2, EMB);
    k_q8  <<<(NN * EMB / 8 + 255) / 256, 256, 0, stream>>>(h2, h2q, NN * EMB / 8);
    k_s2  <<<(NN + 255) / 256, 256, 0, stream>>>(h2, ao, s21, s22);
    k_agg2<<<NN / 4, 256, 0, stream>>>(h2q, s21, s22, rp, sdst, den2, out);

    // outputs 1 & 2 (fused)
    k_att_edge<<<(2 * NE + 255) / 256, 256, 0, stream>>>(ei, s21, s22, den2,
                                                         out + (size_t)NN * EMB,
                                                         out + (size_t)NN * EMB + 2 * NE);
}

// Round 7
// 330.065 us; speedup vs baseline: 2.5583x; 1.2797x over previous
//
#include <hip/hip_runtime.h>
#include <hip/hip_bf16.h>
#include <cstddef>

#define NN    50000
#define NE    800000
#define FIN   256
#define HID   64
#define NH    8
#define F1    512      // NH*HID
#define EMB   128
#define ALPHA 0.2f
#define EPSF  1e-16f
#define NBLK  ((NN + 255) / 256)   // 196

typedef __hip_bfloat16 bf16;
typedef __attribute__((ext_vector_type(8))) short short8;
typedef __attribute__((ext_vector_type(4))) float f32x4;
typedef __attribute__((ext_vector_type(2))) float f32x2;

__device__ __forceinline__ float eluf(float x){ return x > 0.f ? x : expm1f(x); }
__device__ __forceinline__ float lrelu_neg_exp(float s){
    float lr = s > 0.f ? s : ALPHA * s;
    return __expf(-lr);
}
__device__ __forceinline__ float b2f(unsigned u){ return __uint_as_float(u << 16); }

// acc[0..7] += e * fp8x8(q)   (OCP e4m3 hardware decode)
__device__ __forceinline__ void fma8q(float* acc, uint2 q, float e){
    f32x2 p0 = __builtin_amdgcn_cvt_pk_f32_fp8(q.x, false);
    f32x2 p1 = __builtin_amdgcn_cvt_pk_f32_fp8(q.x, true);
    f32x2 p2 = __builtin_amdgcn_cvt_pk_f32_fp8(q.y, false);
    f32x2 p3 = __builtin_amdgcn_cvt_pk_f32_fp8(q.y, true);
    acc[0] += e * p0[0]; acc[1] += e * p0[1];
    acc[2] += e * p1[0]; acc[3] += e * p1[1];
    acc[4] += e * p2[0]; acc[5] += e * p2[1];
    acc[6] += e * p3[0]; acc[7] += e * p3[1];
}
// pack two floats as bf16 pair (RNE)
__device__ __forceinline__ unsigned bpack(float a, float b){
    unsigned ua = __float_as_uint(a), ub = __float_as_uint(b);
    ua = (ua + 0x7fffu + ((ua >> 16) & 1)) >> 16;
    ub = (ub + 0x7fffu + ((ub >> 16) & 1)) >> 16;
    return (ua & 0xffffu) | (ub << 16);
}

// ---------------- input conversions ----------------
__global__ void k_cvt_x(const float* __restrict__ x, bf16* __restrict__ xb){
    int i = blockIdx.x * 256 + threadIdx.x;          // one thread = 8 elems
    if (i >= NN * FIN / 8) return;
    const float4* xp = (const float4*)(x + (size_t)i * 8);
    float4 v0 = xp[0], v1 = xp[1];
    uint4 o;
    o.x = bpack(v0.x, v0.y); o.y = bpack(v0.z, v0.w);
    o.z = bpack(v1.x, v1.y); o.w = bpack(v1.z, v1.w);
    *(uint4*)(xb + (size_t)i * 8) = o;
}

// bf16[8] -> fp8 e4m3[8] (HW encode), one thread = 8 elems
__global__ void k_q8(const bf16* __restrict__ in, unsigned char* __restrict__ out, int n8){
    int i = blockIdx.x * 256 + threadIdx.x;
    if (i >= n8) return;
    uint4 v = *(const uint4*)(in + (size_t)i * 8);
    float f0 = b2f(v.x & 0xffffu), f1 = b2f(v.x >> 16);
    float f2 = b2f(v.y & 0xffffu), f3 = b2f(v.y >> 16);
    float f4 = b2f(v.z & 0xffffu), f5 = b2f(v.z >> 16);
    float f6 = b2f(v.w & 0xffffu), f7 = b2f(v.w >> 16);
    unsigned lo = 0, hi = 0;
    lo = __builtin_amdgcn_cvt_pk_fp8_f32(f0, f1, lo, false);
    lo = __builtin_amdgcn_cvt_pk_fp8_f32(f2, f3, lo, true);
    hi = __builtin_amdgcn_cvt_pk_fp8_f32(f4, f5, hi, false);
    hi = __builtin_amdgcn_cvt_pk_fp8_f32(f6, f7, hi, true);
    uint2 o; o.x = lo; o.y = hi;
    *(uint2*)(out + (size_t)i * 8) = o;
}

// Bt1[n][k] = W1[n>>6][k][n&63]   (512 x 256, bf16)
__global__ void k_tw1(const float* __restrict__ W1, bf16* __restrict__ Bt1){
    int i = blockIdx.x * 256 + threadIdx.x;
    if (i >= F1 * FIN) return;
    int n = i >> 8, k = i & 255;
    Bt1[i] = __float2bfloat16(W1[(size_t)(n >> 6) * FIN * HID + (size_t)k * HID + (n & 63)]);
}

// WoT[n][k] = Wo[k][n]   (128 x 512, bf16)
__global__ void k_tw2(const float* __restrict__ Wo, bf16* __restrict__ WoT){
    int i = blockIdx.x * 256 + threadIdx.x;
    if (i >= EMB * F1) return;
    int n = i >> 9, k = i & 511;
    WoT[i] = __float2bfloat16(Wo[(size_t)k * EMB + n]);
}

// ---------------- CSR build ----------------
__global__ void k_zero(int* p, int n){
    int i = blockIdx.x * 256 + threadIdx.x;
    if (i < n) p[i] = 0;
}

__global__ void k_count(const int* __restrict__ src, int* __restrict__ cnt){
    int e = blockIdx.x * 256 + threadIdx.x;
    if (e < NE) atomicAdd(&cnt[src[e]], 1);
}

// block sums of cnt (256 nodes per block)
__global__ __launch_bounds__(256) void k_bsum(const int* __restrict__ cnt, int* __restrict__ bsum){
    const int b = blockIdx.x, t = threadIdx.x, idx = b * 256 + t;
    int v = (idx < NN) ? cnt[idx] : 0;
#pragma unroll
    for (int o = 1; o < 64; o <<= 1) v += __shfl_xor(v, o);
    __shared__ int ws[4];
    if ((t & 63) == 0) ws[t >> 6] = v;
    __syncthreads();
    if (t == 0) bsum[b] = ws[0] + ws[1] + ws[2] + ws[3];
}

// exclusive scan of the NBLK block sums (single tiny block); also writes rp[NN]
__global__ __launch_bounds__(256) void k_scanb(const int* __restrict__ bsum,
                                               int* __restrict__ boff,
                                               int* __restrict__ rp){
    const int t = threadIdx.x;
    __shared__ int s[256];
    const int v = (t < NBLK) ? bsum[t] : 0;
    s[t] = v;
    __syncthreads();
    for (int o = 1; o < 256; o <<= 1){
        int u = (t >= o) ? s[t - o] : 0;
        __syncthreads();
        s[t] += u;
        __syncthreads();
    }
    if (t < NBLK) boff[t] = s[t] - v;      // exclusive
    if (t == 255) rp[NN] = s[255];         // == NE
}

// per-block exclusive scan + block offset -> rp
__global__ __launch_bounds__(256) void k_rp(const int* __restrict__ cnt,
                                            const int* __restrict__ boff,
                                            int* __restrict__ rp){
    const int b = blockIdx.x, t = threadIdx.x, idx = b * 256 + t;
    const int v = (idx < NN) ? cnt[idx] : 0;
    __shared__ int s[256];
    s[t] = v;
    __syncthreads();
    for (int o = 1; o < 256; o <<= 1){
        int u = (t >= o) ? s[t - o] : 0;
        __syncthreads();
        s[t] += u;
        __syncthreads();
    }
    if (idx < NN) rp[idx] = boff[b] + s[t] - v;
}

__global__ void k_scatter(const int* __restrict__ src, const int* __restrict__ dst,
                          const int* __restrict__ rp, int* __restrict__ cur,
                          int* __restrict__ sdst){
    int e = blockIdx.x * 256 + threadIdx.x;
    if (e < NE){
        int s = src[e];
        int p = atomicAdd(&cur[s], 1);
        sdst[rp[s] + p] = dst[e];
    }
}

// ---------------- MFMA GEMM: C[M][N] = A[M][K] @ B^T[N][K], bf16 in/out ----------------
template<int K>
__global__ __launch_bounds__(256) void k_mgemm(const bf16* __restrict__ A,
                                               const bf16* __restrict__ B,
                                               bf16* __restrict__ C,
                                               int N){
    constexpr int LDT = 40;                     // bf16 elems per LDS row (80B, conflict-free)
    __shared__ __align__(16) bf16 As[128 * LDT];
    __shared__ __align__(16) bf16 Bs[128 * LDT];
    const int t = threadIdx.x;
    const int lane = t & 63, wid = t >> 6;
    const int m0 = blockIdx.x * 128, n0 = blockIdx.y * 128;
    const int r0 = t >> 2, u0 = t & 3;          // rows 0..63
    const int r1 = r0 + 64;                     // rows 64..127
    const int rb = (wid & 1) * 64, cb = (wid >> 1) * 64;
    const int fr = lane & 15, fk = (lane >> 4) * 8;

    f32x4 acc[4][4];
#pragma unroll
    for (int i = 0; i < 4; i++)
#pragma unroll
        for (int j = 0; j < 4; j++) acc[i][j] = (f32x4)(0.f);

    for (int k0 = 0; k0 < K; k0 += 32){
        const int ga0 = m0 + r0, ga1 = m0 + r1;
        uint4 av0 = (ga0 < NN) ? *(const uint4*)(A + (size_t)ga0 * K + k0 + u0 * 8)
                               : make_uint4(0, 0, 0, 0);
        uint4 av1 = (ga1 < NN) ? *(const uint4*)(A + (size_t)ga1 * K + k0 + u0 * 8)
                               : make_uint4(0, 0, 0, 0);
        uint4 bv0 = *(const uint4*)(B + (size_t)(n0 + r0) * K + k0 + u0 * 8);
        uint4 bv1 = *(const uint4*)(B + (size_t)(n0 + r1) * K + k0 + u0 * 8);
        __syncthreads();
        *(uint4*)(As + r0 * LDT + u0 * 8) = av0;
        *(uint4*)(As + r1 * LDT + u0 * 8) = av1;
        *(uint4*)(Bs + r0 * LDT + u0 * 8) = bv0;
        *(uint4*)(Bs + r1 * LDT + u0 * 8) = bv1;
        __syncthreads();
        short8 af[4], bf_[4];
#pragma unroll
        for (int i = 0; i < 4; i++){
            af[i]  = *(const short8*)(As + (rb + i * 16 + fr) * LDT + fk);
            bf_[i] = *(const short8*)(Bs + (cb + i * 16 + fr) * LDT + fk);
        }
#pragma unroll
        for (int i = 0; i < 4; i++)
#pragma unroll
            for (int j = 0; j < 4; j++)
                acc[i][j] = __builtin_amdgcn_mfma_f32_16x16x32_bf16(af[i], bf_[j], acc[i][j], 0, 0, 0);
    }
    const int crow = m0 + rb + (lane >> 4) * 4;
    const int ccol = n0 + cb + (lane & 15);
#pragma unroll
    for (int i = 0; i < 4; i++)
#pragma unroll
        for (int j = 0; j < 4; j++)
#pragma unroll
            for (int v = 0; v < 4; v++){
                int row = crow + i * 16 + v;
                if (row < NN)
                    C[(size_t)row * N + ccol + j * 16] = __float2bfloat16(acc[i][j][v]);
            }
}

// ---------------- per-node attention scalars, layer 1 ----------------
__global__ void k_s1(const bf16* __restrict__ h1, const float* __restrict__ a1,
                     float* __restrict__ s11, float* __restrict__ s12){
    int idx = blockIdx.x * 256 + threadIdx.x;
    if (idx >= NN * NH) return;
    int n = idx >> 3, h = idx & 7;
    const uint4* hp = (const uint4*)(h1 + (size_t)n * F1 + h * HID);
    const float* a  = a1 + (size_t)h * 2 * HID;
    float d1 = 0.f, d2 = 0.f;
#pragma unroll
    for (int u = 0; u < 8; u++){
        uint4 v = hp[u];
        int j = u * 8;
        float f0 = b2f(v.x & 0xffffu), f1 = b2f(v.x >> 16);
        float f2 = b2f(v.y & 0xffffu), f3 = b2f(v.y >> 16);
        float f4 = b2f(v.z & 0xffffu), f5 = b2f(v.z >> 16);
        float f6 = b2f(v.w & 0xffffu), f7 = b2f(v.w >> 16);
        d1 += f0 * a[j]     + f1 * a[j + 1] + f2 * a[j + 2] + f3 * a[j + 3]
            + f4 * a[j + 4] + f5 * a[j + 5] + f6 * a[j + 6] + f7 * a[j + 7];
        d2 += f0 * a[HID + j]     + f1 * a[HID + j + 1] + f2 * a[HID + j + 2] + f3 * a[HID + j + 3]
            + f4 * a[HID + j + 4] + f5 * a[HID + j + 5] + f6 * a[HID + j + 6] + f7 * a[HID + j + 7];
    }
    s11[idx] = d1;   // layout [n][h]
    s12[idx] = d2;
}

// ---------------- layer-1 aggregation: one WAVE per node, fp8 gather payload ----------
__global__ __launch_bounds__(256) void k_agg1(const unsigned char* __restrict__ h1q,
                                              const float* __restrict__ s11,
                                              const float* __restrict__ s12,
                                              const int* __restrict__ rp,
                                              const int* __restrict__ sdst,
                                              bf16* __restrict__ x1){
    const int t = threadIdx.x, lane = t & 63, w = t >> 6;
    const int n = blockIdx.x * 4 + w;
    const int ha = lane & 7;        // head for ee-compute role
    const int hf = lane >> 3;       // head of owned features
    const float s1a = s11[n * NH + ha];
    float acc[8] = {0.f,0.f,0.f,0.f,0.f,0.f,0.f,0.f};
    float dedp = 0.f;
    const int start = rp[n], end = rp[n + 1];
    const unsigned char* __restrict__ h1l = h1q + (size_t)lane * 8;   // lane-fixed base
    for (int c0 = start; c0 < end; c0 += 64){
        const int m = min(64, end - c0);
        int dreg = (lane < m) ? sdst[c0 + lane] : 0;
        const int full = m & ~7;
        for (int sc = 0; sc < full; sc += 8){
            int de = __shfl(dreg, sc + hf);             // edge sc+(lane>>3)
            float ev = lrelu_neg_exp(s1a + s12[de * NH + ha]);
            dedp += ev;
#pragma unroll
            for (int j = 0; j < 8; j++){
                int   dj = __shfl(dreg, sc + j);
                float ej = __shfl(ev, j * 8 + hf);
                uint2 q = *(const uint2*)(h1l + (size_t)dj * F1);
                fma8q(acc, q, ej);
            }
        }
        if (full < m){
            int eloc = full + hf;                       // <= 63
            int de = __shfl(dreg, eloc);
            float ev = (eloc < m) ? lrelu_neg_exp(s1a + s12[de * NH + ha]) : 0.f;
            dedp += ev;
            const int mm = m - full;
            for (int j = 0; j < mm; j++){
                int   dj = __shfl(dreg, full + j);
                float ej = __shfl(ev, j * 8 + hf);
                uint2 q = *(const uint2*)(h1l + (size_t)dj * F1);
                fma8q(acc, q, ej);
            }
        }
    }
    // reduce dedp over the 8 edge-slots (lane bits 3..5); lane l then holds ded[l&7]
    dedp += __shfl_xor(dedp, 8);
    dedp += __shfl_xor(dedp, 16);
    dedp += __shfl_xor(dedp, 32);
    float ded = __shfl(dedp, hf);                       // ded for my feature head
    const float inv = 1.f / (ded + EPSF);
    float o[8];
#pragma unroll
    for (int i = 0; i < 8; i++) o[i] = eluf(acc[i] * inv);
    uint4 ov;
    ov.x = bpack(o[0], o[1]); ov.y = bpack(o[2], o[3]);
    ov.z = bpack(o[4], o[5]); ov.w = bpack(o[6], o[7]);
    *(uint4*)(x1 + (size_t)n * F1 + lane * 8) = ov;
}

// ---------------- per-node attention scalars, layer 2 (bf16 h2) ----------------
__global__ void k_s2(const bf16* __restrict__ h2, const float* __restrict__ ao,
                     float* __restrict__ s21, float* __restrict__ s22){
    int n = blockIdx.x * 256 + threadIdx.x;
    if (n >= NN) return;
    const uint4* hp = (const uint4*)(h2 + (size_t)n * EMB);
    float d1 = 0.f, d2 = 0.f;
#pragma unroll
    for (int u = 0; u < 16; u++){
        uint4 v = hp[u];
        int j = u * 8;
        float f0 = b2f(v.x & 0xffffu), f1 = b2f(v.x >> 16);
        float f2 = b2f(v.y & 0xffffu), f3 = b2f(v.y >> 16);
        float f4 = b2f(v.z & 0xffffu), f5 = b2f(v.z >> 16);
        float f6 = b2f(v.w & 0xffffu), f7 = b2f(v.w >> 16);
        d1 += f0 * ao[j]     + f1 * ao[j + 1] + f2 * ao[j + 2] + f3 * ao[j + 3]
            + f4 * ao[j + 4] + f5 * ao[j + 5] + f6 * ao[j + 6] + f7 * ao[j + 7];
        d2 += f0 * ao[EMB + j]     + f1 * ao[EMB + j + 1] + f2 * ao[EMB + j + 2] + f3 * ao[EMB + j + 3]
            + f4 * ao[EMB + j + 4] + f5 * ao[EMB + j + 5] + f6 * ao[EMB + j + 6] + f7 * ao[EMB + j + 7];
    }
    s21[n] = d1;
    s22[n] = d2;
}

// ---------------- layer-2 aggregation: one WAVE per node, fp8 payload ----------------
__global__ __launch_bounds__(256) void k_agg2(const unsigned char* __restrict__ h2q,
                                              const float* __restrict__ s21,
                                              const float* __restrict__ s22,
                                              const int* __restrict__ rp,
                                              const int* __restrict__ sdst,
                                              float* __restrict__ den2,
                                              float* __restrict__ out0){
    const int t = threadIdx.x, lane = t & 63, w = t >> 6;
    const int n = blockIdx.x * 4 + w;
    const int slot = lane >> 4, fl = (lane & 15) * 8;
    const float s1v = s21[n];
    float acc[8] = {0.f,0.f,0.f,0.f,0.f,0.f,0.f,0.f};
    float dedp = 0.f;
    const int start = rp[n], end = rp[n + 1];
    const unsigned char* __restrict__ h2l = h2q + fl;
    for (int c0 = start; c0 < end; c0 += 64){
        const int m = min(64, end - c0);
        int dreg = (lane < m) ? sdst[c0 + lane] : 0;
        // each lane computes ee for ITS edge once
        float ev = (lane < m) ? lrelu_neg_exp(s1v + s22[dreg]) : 0.f;
        dedp += ev;
        for (int j = slot; j < m; j += 4){
            int   d = __shfl(dreg, j);
            float e = __shfl(ev, j);
            uint2 q = *(const uint2*)(h2l + (size_t)d * EMB);
            fma8q(acc, q, e);
        }
    }
    // denominator: full 64-lane reduction
#pragma unroll
    for (int o = 1; o <= 32; o <<= 1) dedp += __shfl_xor(dedp, o);
    // acc: reduce across the 4 slots
#pragma unroll
    for (int o = 16; o <= 32; o <<= 1)
#pragma unroll
        for (int i = 0; i < 8; i++) acc[i] += __shfl_xor(acc[i], o);
    const float den = dedp + EPSF;
    if (slot == 0){
        const float inv = 1.f / den;
        float4 o0, o1;
        o0.x = eluf(acc[0] * inv); o0.y = eluf(acc[1] * inv);
        o0.z = eluf(acc[2] * inv); o0.w = eluf(acc[3] * inv);
        o1.x = eluf(acc[4] * inv); o1.y = eluf(acc[5] * inv);
        o1.z = eluf(acc[6] * inv); o1.w = eluf(acc[7] * inv);
        float* op = out0 + (size_t)n * EMB + fl;
        *(float4*)op = o0;
        *(float4*)(op + 4) = o1;
        if (lane == 0) den2[n] = den;
    }
}

// ---------------- fused: edge_index copy + att_out (original edge order) ----------------
__global__ void k_att_edge(const int* __restrict__ ei,
                           const float* __restrict__ s21, const float* __restrict__ s22,
                           const float* __restrict__ den2,
                           float* __restrict__ outE, float* __restrict__ outA){
    int i = blockIdx.x * 256 + threadIdx.x;
    if (i < 2 * NE) outE[i] = (float)ei[i];
    if (i < NE){
        int s = ei[i], d = ei[NE + i];
        float ee = lrelu_neg_exp(s21[s] + s22[d]);
        outA[i] = ee / den2[s];
    }
}

// ---------------- launch ----------------
extern "C" void kernel_launch(void* const* d_in, const int* in_sizes, int n_in,
                              void* d_out, int out_size, void* d_ws, size_t ws_size,
                              hipStream_t stream){
    const float* x  = (const float*)d_in[0];
    const int*   ei = (const int*)d_in[1];
    const float* W1 = (const float*)d_in[2];
    const float* a1 = (const float*)d_in[3];
    const float* Wo = (const float*)d_in[4];
    const float* ao = (const float*)d_in[5];
    float* out = (float*)d_out;
    const int* src = ei;
    const int* dst = ei + NE;

    char* w = (char*)d_ws;
    auto alloc = [&](size_t bytes) -> char* {
        char* p = w;
        w += (bytes + 255) & ~(size_t)255;
        return p;
    };
    bf16*  xb   = (bf16*) alloc((size_t)NN * FIN * 2);  // 25.6 MB
    bf16*  h1   = (bf16*) alloc((size_t)NN * F1 * 2);   // 51.2 MB
    bf16*  x1   = (bf16*) alloc((size_t)NN * F1 * 2);   // 51.2 MB
    float* s11  = (float*)alloc((size_t)NN * NH * 4);
    float* s12  = (float*)alloc((size_t)NN * NH * 4);
    float* s21  = (float*)alloc((size_t)NN * 4);
    float* s22  = (float*)alloc((size_t)NN * 4);
    float* den2 = (float*)alloc((size_t)NN * 4);
    int*   cnt2 = (int*)  alloc((size_t)2 * NN * 4);
    int*   rp   = (int*)  alloc((size_t)(NN + 1) * 4);
    int*   sdst = (int*)  alloc((size_t)NE * 4);
    int*   bsum = (int*)  alloc((size_t)NBLK * 4);
    int*   boff = (int*)  alloc((size_t)NBLK * 4);
    int*   cnt = cnt2;
    int*   cur = cnt2 + NN;
    // lifetime-disjoint aliases:
    bf16* Bt1 = x1;                         // dead before k_agg1 writes x1
    bf16* WoT = (bf16*)s21;                 // dead before k_s2 writes s21
    bf16* h2  = h1;                         // h1 dead after k_agg1
    unsigned char* h1q = (unsigned char*)xb;  // xb dead after gemm1 (25.6 MB exact)
    unsigned char* h2q = (unsigned char*)x1;  // x1 dead after gemm2 (needs 6.4 MB)

    // input conversion / weight transposes
    k_cvt_x<<<(NN * FIN / 8 + 255) / 256, 256, 0, stream>>>(x, xb);
    k_tw1  <<<(F1 * FIN + 255) / 256,     256, 0, stream>>>(W1, Bt1);
    k_tw2  <<<(EMB * F1 + 255) / 256,     256, 0, stream>>>(Wo, WoT);

    // CSR build (device-wide 3-kernel scan replaces the single-block scan)
    k_zero   <<<(2 * NN + 255) / 256, 256, 0, stream>>>(cnt2, 2 * NN);
    k_count  <<<(NE + 255) / 256,     256, 0, stream>>>(src, cnt);
    k_bsum   <<<NBLK,                 256, 0, stream>>>(cnt, bsum);
    k_scanb  <<<1,                    256, 0, stream>>>(bsum, boff, rp);
    k_rp     <<<NBLK,                 256, 0, stream>>>(cnt, boff, rp);
    k_scatter<<<(NE + 255) / 256,     256, 0, stream>>>(src, dst, rp, cur, sdst);

    // layer 1
    k_mgemm<FIN><<<dim3((NN + 127) / 128, F1 / 128), 256, 0, stream>>>(xb, Bt1, h1, F1);
    k_q8  <<<(NN * F1 / 8 + 255) / 256, 256, 0, stream>>>(h1, h1q, NN * F1 / 8);
    k_s1  <<<(NN * NH + 255) / 256, 256, 0, stream>>>(h1, a1, s11, s12);
    k_agg1<<<NN / 4, 256, 0, stream>>>(h1q, s11, s12, rp, sdst, x1);

    // layer 2
    k_mgemm<F1><<<dim3((NN + 127) / 128, EMB / 128), 256, 0, stream>>>(x1, WoT, h2, EMB);
    k_q8  <<<(NN * EMB / 8 + 255) / 256, 256, 0, stream>>>(h2, h2q, NN * EMB / 8);
    k_s2  <<<(NN + 255) / 256, 256, 0, stream>>>(h2, ao, s21, s22);
    k_agg2<<<NN / 4, 256, 0, stream>>>(h2q, s21, s22, rp, sdst, den2, out);

    // outputs 1 & 2 (fused)
    k_att_edge<<<(2 * NE + 255) / 256, 256, 0, stream>>>(ei, s21, s22, den2,
                                                         out + (size_t)NN * EMB,
                                                         out + (size_t)NN * EMB + 2 * NE);
}